// Round 15
// baseline (119.638 us; speedup 1.0000x reference)
//
#include <hip/hip_runtime.h>
#include <cmath>

typedef unsigned short u16;
typedef unsigned short u16x4 __attribute__((ext_vector_type(4)));
typedef unsigned short u16x8 __attribute__((ext_vector_type(8)));
typedef __bf16 bf16x8 __attribute__((ext_vector_type(8)));
typedef float f32x4 __attribute__((ext_vector_type(4)));

#define HNUM 8
#define HDIM 64
#define BATCH 4
#define NSEQ 2048
#define DMODEL 512
#define LP 72    // padded LDS row stride (u16) for attn P buffer
#define CPE 264  // padded C-tile row stride (u16) in gemm_fused epilogue
#define NSLOT 14 // split partial slots per (b,qt): h0 x8 + h1 x4 + h2 x2

__device__ __forceinline__ u16 f2bf(float f) {
  unsigned int u = __builtin_bit_cast(unsigned int, f);
  u += 0x7fffu + ((u >> 16) & 1u);          // round-to-nearest-even
  return (u16)(u >> 16);
}

__device__ __forceinline__ float bf2f(u16 v) {
  unsigned int u = ((unsigned int)v) << 16;
  return __builtin_bit_cast(float, u);
}

__device__ __forceinline__ f32x4 mfma_bf16(u16x8 a, u16x8 b, f32x4 c) {
  return __builtin_amdgcn_mfma_f32_16x16x32_bf16(
      __builtin_bit_cast(bf16x8, a), __builtin_bit_cast(bf16x8, b), c, 0, 0, 0);
}

// async global->LDS, 16 B per lane (dest must be wave-uniform base + lane*16)
__device__ __forceinline__ void gload16(u16* lds, const u16* g) {
  __builtin_amdgcn_global_load_lds(
      (const __attribute__((address_space(1))) void*)g,
      (__attribute__((address_space(3))) void*)lds, 16, 0, 0);
}

// chunk-XOR swizzle (rounds 10-14 verified): linear LDS dest, inverse-swizzled
// global source; read with the same XOR. 32-col (BK=32) tiles.
__device__ __forceinline__ int swz_off(int row, int lg) {
  return row * 32 + ((lg ^ ((row >> 1) & 3)) << 3);
}

// 256-thread staging (gemm_out)
template <int ROWS>
__device__ __forceinline__ void stage_tile(u16* lds, const u16* g, int tid) {
  #pragma unroll
  for (int i = 0; i < ROWS / 64; ++i) {
    const int t = i * 256 + tid;
    const int row = t >> 2;
    const int ch = (t & 3) ^ ((row >> 1) & 3);
    gload16(lds + t * 8, g + (size_t)row * DMODEL + ch * 8);
  }
}

// 512-thread staging of A(128x32) + B(256x32), 3 loads/thread
__device__ __forceinline__ void stageAB(u16* ldsA, u16* ldsB, const u16* gA,
                                        const u16* gB, int tid) {
  {
    const int s = tid;                       // A: 512 loads
    const int row = s >> 2;
    const int ch = (s & 3) ^ ((row >> 1) & 3);
    gload16(ldsA + s * 8, gA + (size_t)row * DMODEL + ch * 8);
  }
  #pragma unroll
  for (int i = 0; i < 2; ++i) {              // B: 1024 loads
    const int s = i * 512 + tid;
    const int row = s >> 2;
    const int ch = (s & 3) ^ ((row >> 1) & 3);
    gload16(ldsB + s * 8, gB + (size_t)row * DMODEL + ch * 8);
  }
}

// ---------------------------------------------------------------------------
// Prep: fp32 -> bf16 convert (x), 8 elems/thread
// ---------------------------------------------------------------------------
__global__ __launch_bounds__(256) void cvt_bf16_kernel(
    const float* __restrict__ in, u16* __restrict__ out, int n8) {
  int i = blockIdx.x * 256 + threadIdx.x;
  if (i >= n8) return;
  const float4 f0 = *(const float4*)(in + i * 8);
  const float4 f1 = *(const float4*)(in + i * 8 + 4);
  u16x8 pk;
  pk[0] = f2bf(f0.x); pk[1] = f2bf(f0.y); pk[2] = f2bf(f0.z); pk[3] = f2bf(f0.w);
  pk[4] = f2bf(f1.x); pk[5] = f2bf(f1.y); pk[6] = f2bf(f1.z); pk[7] = f2bf(f1.w);
  *(u16x8*)(out + i * 8) = pk;
}

// ---------------------------------------------------------------------------
// Prep: all three weight transposes in ONE kernel.
// blockIdx.x: 0-47 qkv_w (N=1536) | 48-63 gate_w | 64-79 out_w.
// ---------------------------------------------------------------------------
__global__ __launch_bounds__(256) void transpose_wall(
    const float* __restrict__ qkv_w, const float* __restrict__ gate_w,
    const float* __restrict__ out_w, u16* __restrict__ fused_wt,
    u16* __restrict__ out_wt) {
  __shared__ float tile[32][33];
  const int bx = blockIdx.x;
  const float* W;
  u16* Wt;
  int N, nb;
  if (bx < 48)      { W = qkv_w;  Wt = fused_wt;                     N = 1536; nb = bx; }
  else if (bx < 64) { W = gate_w; Wt = fused_wt + (size_t)1536 * 512; N = 512;  nb = bx - 48; }
  else              { W = out_w;  Wt = out_wt;                       N = 512;  nb = bx - 64; }
  const int n0 = nb * 32, k0 = blockIdx.y * 32;
  const int tx = threadIdx.x & 31, ty = threadIdx.x >> 5;
  #pragma unroll
  for (int yy = ty; yy < 32; yy += 8)
    tile[yy][tx] = W[(size_t)(k0 + yy) * N + n0 + tx];
  __syncthreads();
  #pragma unroll
  for (int yy = ty; yy < 32; yy += 8)
    Wt[(size_t)(n0 + yy) * DMODEL + k0 + tx] = f2bf(tile[tx][yy]);
}

// ---------------------------------------------------------------------------
// Prep: vbf[b,h,n,d] -> vbfT[b,h,d,n] (64x64 LDS tile transpose)
// ---------------------------------------------------------------------------
__global__ __launch_bounds__(256) void transpose_v_kernel(
    const u16* __restrict__ v, u16* __restrict__ vT) {
  __shared__ u16 t[64][LP];
  const int n0 = blockIdx.x * 64;
  const size_t bh = blockIdx.y;
  const int r = threadIdx.x >> 2, c0 = (threadIdx.x & 3) << 4;
  const u16* src = v + (bh * NSEQ + n0 + r) * HDIM + c0;
  u16x8 a0 = *(const u16x8*)src;
  u16x8 a1 = *(const u16x8*)(src + 8);
  #pragma unroll
  for (int j = 0; j < 8; ++j) {
    t[c0 + j][r] = a0[j];
    t[c0 + 8 + j][r] = a1[j];
  }
  __syncthreads();
  u16x8 o0 = *(const u16x8*)&t[r][c0];
  u16x8 o1 = *(const u16x8*)&t[r][c0 + 8];
  u16* dst = vT + (bh * HDIM + r) * NSEQ + n0 + c0;
  *(u16x8*)dst = o0;
  *(u16x8*)(dst + 8) = o1;
}

// ---------------------------------------------------------------------------
// Bias table: tab[h][d] = in_band(bucket(d),h) ? pos_bias[bucket(d)][h] : -100
// ---------------------------------------------------------------------------
__global__ __launch_bounds__(256) void bias_tab_kernel(
    const float* __restrict__ pos_bias, float* __restrict__ tab) {
  int d = blockIdx.x * 256 + threadIdx.x;   // 0..2047
  if (d >= NSEQ) return;
  int bkt;
  if (d < 28) {
    bkt = d;
  } else {
    double t = log((double)d / 28.0) / log(2048.0 / 28.0) * 16.0;
    int ti = 28 + (int)t;
    bkt = ti < 43 ? ti : 43;
  }
  const int lo[8] = {38, 34, 28, 20, 13, 7, 3, 0};
  const int hi[8] = {44, 40, 35, 28, 21, 14, 9, 6};
  #pragma unroll
  for (int h = 0; h < HNUM; ++h) {
    bool inb = (bkt >= lo[h]) && (bkt < hi[h]);
    tab[h * NSEQ + d] = inb ? pos_bias[bkt * HNUM + h] : -100.0f;
  }
}

// ---------------------------------------------------------------------------
// Fused qkv+gate GEMM: 128x256 tile, BK=32, 512 threads, 2 blocks/CU,
// single-barrier 3-deep counted-vmcnt loop (round-14 verified).
// ---------------------------------------------------------------------------
__global__ __launch_bounds__(512, 4) void gemm_fused(
    const u16* __restrict__ Abf, const u16* __restrict__ Wt,
    const float* __restrict__ qkv_b, const float* __restrict__ gate_b,
    const float* __restrict__ kdelta, const float* __restrict__ vdelta,
    u16* __restrict__ qbf, u16* __restrict__ kbf, u16* __restrict__ vbf,
    u16* __restrict__ gate) {
  __shared__ __align__(16) u16 S[36864];   // 72 KB
  u16* SA3[3] = {S, S + 4096, S + 8192};
  u16* SB3[3] = {S + 12288, S + 20480, S + 28672};

  // XCD band map: XCD x owns m-tiles 8x..8x+7 (1MB A) x all n (2MB W)
  const int bid = blockIdx.x;
  const int xcd = bid & 7, loc = bid >> 3;
  const int m0 = (xcd * 8 + (loc & 7)) * 128;
  const int n0 = (loc >> 3) * 256;

  const int tid = threadIdx.x;
  const int w = tid >> 6, l = tid & 63, li = l & 15, lg = l >> 4;
  const int wm = w >> 2, wn = w & 3;

  f32x4 acc[4][4];
  #pragma unroll
  for (int i = 0; i < 4; ++i)
    #pragma unroll
    for (int j = 0; j < 4; ++j) acc[i][j] = f32x4{0.f, 0.f, 0.f, 0.f};

  const u16* Ab = Abf + (size_t)m0 * DMODEL;
  const u16* Bb = Wt + (size_t)n0 * DMODEL;

  stageAB(SA3[0], SB3[0], Ab, Bb, tid);
  stageAB(SA3[1], SB3[1], Ab + 32, Bb + 32, tid);

  #pragma unroll
  for (int kt = 0; kt < 16; ++kt) {
    if (kt <= 14) asm volatile("s_waitcnt vmcnt(3)" ::: "memory");
    else          asm volatile("s_waitcnt vmcnt(0)" ::: "memory");
    __builtin_amdgcn_s_barrier();        // all waves done reading tile kt-1
    __builtin_amdgcn_sched_barrier(0);
    if (kt + 2 < 16)                     // safe: buffer (kt+2)%3 = (kt-1)%3
      stageAB(SA3[(kt + 2) % 3], SB3[(kt + 2) % 3],
              Ab + (kt + 2) * 32, Bb + (kt + 2) * 32, tid);
    const u16* Asb = SA3[kt % 3];
    const u16* Bsb = SB3[kt % 3];
    u16x8 af[4], bfr[4];
    #pragma unroll
    for (int mt = 0; mt < 4; ++mt)
      af[mt] = *(const u16x8*)&Asb[swz_off(wm * 64 + mt * 16 + li, lg)];
    #pragma unroll
    for (int nt = 0; nt < 4; ++nt)
      bfr[nt] = *(const u16x8*)&Bsb[swz_off(wn * 64 + nt * 16 + li, lg)];
    asm volatile("s_waitcnt lgkmcnt(0)" ::: "memory");
    __builtin_amdgcn_sched_barrier(0);
    #pragma unroll
    for (int mt = 0; mt < 4; ++mt)
      #pragma unroll
      for (int nt = 0; nt < 4; ++nt)
        acc[mt][nt] = mfma_bf16(af[mt], bfr[nt], acc[mt][nt]);
  }
  __syncthreads();                       // all reads done before S reuse

  // ---- epilogue: acc+bias -> padded LDS C-tile (128x256, stride CPE) ----
  u16* Ct = S;
  const int seg = n0 >> 9;                   // 0=q 1=k 2=v 3=gate (uniform)
  const int nin = n0 & 511;                  // 0 or 256
  #pragma unroll
  for (int nt = 0; nt < 4; ++nt) {
    const int col = wn * 64 + nt * 16 + li;
    const int colg = n0 + col;
    const float bv = (seg < 3) ? qkv_b[colg] : gate_b[colg & 511];
    #pragma unroll
    for (int mt = 0; mt < 4; ++mt) {
      const int row = wm * 64 + mt * 16 + lg * 4;
      #pragma unroll
      for (int r = 0; r < 4; ++r)
        Ct[(row + r) * CPE + col] = f2bf(acc[mt][nt][r] + bv);
    }
  }
  __syncthreads();

  // ---- packed coalesced writes from LDS (8 u16x8 per thread) ----
  #pragma unroll
  for (int p = 0; p < 8; ++p) {
    const int idx = p * 512 + tid;
    const int row = idx >> 5, ccol = (idx & 31) * 8;
    const int rg = m0 + row;
    const int bb = rg >> 11, n = rg & 2047;
    u16x8 cv = *(const u16x8*)&Ct[row * CPE + ccol];
    const int cws = nin + ccol;              // col within 512-wide segment
    if (seg == 3) {
      u16x8 o;
      #pragma unroll
      for (int j = 0; j < 8; ++j)
        o[j] = f2bf(1.f / (1.f + __expf(-bf2f(cv[j]))));
      *(u16x8*)&gate[(size_t)rg * DMODEL + cws] = o;
    } else {
      const int hh = cws >> 6, hd = cws & 63;
      const size_t hidx = (((size_t)bb * HNUM + hh) * NSEQ + n) * HDIM + hd;
      if (seg == 0) {
        u16x8 o;
        #pragma unroll
        for (int j = 0; j < 8; ++j) o[j] = f2bf(bf2f(cv[j]) * 0.125f);
        *(u16x8*)&qbf[hidx] = o;
      } else {
        const float* dp = (seg == 1 ? kdelta : vdelta) + hidx;
        float4 d0 = *(const float4*)dp;
        float4 d1 = *(const float4*)(dp + 4);
        u16x8 o;
        o[0] = f2bf(bf2f(cv[0]) + d0.x); o[1] = f2bf(bf2f(cv[1]) + d0.y);
        o[2] = f2bf(bf2f(cv[2]) + d0.z); o[3] = f2bf(bf2f(cv[3]) + d0.w);
        o[4] = f2bf(bf2f(cv[4]) + d1.x); o[5] = f2bf(bf2f(cv[5]) + d1.y);
        o[6] = f2bf(bf2f(cv[6]) + d1.z); o[7] = f2bf(bf2f(cv[7]) + d1.w);
        *(u16x8*)&((seg == 1) ? kbf : vbf)[hidx] = o;
      }
    }
  }
}

// ---------------------------------------------------------------------------
// Out GEMM: 64x128 tile, BK=32, single-barrier 3-deep loop (verified).
// ---------------------------------------------------------------------------
__global__ __launch_bounds__(256) void gemm_out(
    const u16* __restrict__ Abf, const u16* __restrict__ Wt,
    const float* __restrict__ bias, float* __restrict__ outf) {
  __shared__ __align__(16) u16 As[3][64 * 32];
  __shared__ __align__(16) u16 Bs[3][128 * 32];

  const int m0 = blockIdx.y * 64, n0 = blockIdx.x * 128;
  const int tid = threadIdx.x;
  const int w = tid >> 6, l = tid & 63, li = l & 15, lg = l >> 4;
  const int wr = w >> 1, wc = w & 1;

  f32x4 acc[2][4];
  #pragma unroll
  for (int i = 0; i < 2; ++i)
    #pragma unroll
    for (int j = 0; j < 4; ++j) acc[i][j] = f32x4{0.f, 0.f, 0.f, 0.f};

  const u16* Ab = Abf + (size_t)m0 * DMODEL;
  const u16* Bb = Wt + (size_t)n0 * DMODEL;

  stage_tile<64>(As[0], Ab, tid);
  stage_tile<128>(Bs[0], Bb, tid);
  stage_tile<64>(As[1], Ab + 32, tid);
  stage_tile<128>(Bs[1], Bb + 32, tid);

  #pragma unroll
  for (int kt = 0; kt < 16; ++kt) {
    if (kt <= 14) asm volatile("s_waitcnt vmcnt(3)" ::: "memory");
    else          asm volatile("s_waitcnt vmcnt(0)" ::: "memory");
    __builtin_amdgcn_s_barrier();
    __builtin_amdgcn_sched_barrier(0);
    if (kt + 2 < 16) {
      stage_tile<64>(As[(kt + 2) % 3], Ab + (kt + 2) * 32, tid);
      stage_tile<128>(Bs[(kt + 2) % 3], Bb + (kt + 2) * 32, tid);
    }
    const u16* Asb = As[kt % 3];
    const u16* Bsb = Bs[kt % 3];
    u16x8 af[2], bfr[4];
    #pragma unroll
    for (int mt = 0; mt < 2; ++mt)
      af[mt] = *(const u16x8*)&Asb[swz_off(wr * 32 + mt * 16 + li, lg)];
    #pragma unroll
    for (int nt = 0; nt < 4; ++nt)
      bfr[nt] = *(const u16x8*)&Bsb[swz_off(wc * 64 + nt * 16 + li, lg)];
    asm volatile("s_waitcnt lgkmcnt(0)" ::: "memory");
    __builtin_amdgcn_sched_barrier(0);
    #pragma unroll
    for (int mt = 0; mt < 2; ++mt)
      #pragma unroll
      for (int nt = 0; nt < 4; ++nt)
        acc[mt][nt] = mfma_bf16(af[mt], bfr[nt], acc[mt][nt]);
  }

  #pragma unroll
  for (int nt = 0; nt < 4; ++nt) {
    const int colg = n0 + wc * 64 + nt * 16 + li;
    const float bv = bias[colg];
    #pragma unroll
    for (int mt = 0; mt < 2; ++mt) {
      #pragma unroll
      for (int r = 0; r < 4; ++r) {
        const int rowg = m0 + wr * 32 + mt * 16 + lg * 4 + r;
        outf[(size_t)rowg * DMODEL + colg] = acc[mt][nt][r] + bv;
      }
    }
  }
}

// ---------------------------------------------------------------------------
// Flash attention, swapped-QK^T, banded KV windows, split-KV balanced chunks.
// NO K/V LDS staging: K and V fragments are read DIRECTLY from global
// (L2-resident: 256 KB per (b,h), shared by many blocks) — zero barriers in
// the KV loop; waves fully independent. P bounces through per-wave LDS with
// lgkmcnt(0)+sched_barrier(0) fence (rule #18).
// Slots: h0 x8 (0-7), h1 x4 (8-11), h2 x2 (12-13), h3..h7 direct (14-18).
// ---------------------------------------------------------------------------
__global__ __launch_bounds__(256) void attn_kernel(
    const u16* __restrict__ qbf, const u16* __restrict__ kbf,
    const u16* __restrict__ vbfT, const float* __restrict__ bias_tab,
    const float* __restrict__ if_gain, const u16* __restrict__ gate,
    u16* __restrict__ attn_out, u16* __restrict__ partO,
    float* __restrict__ partM, float* __restrict__ partL) {
  __shared__ __align__(16) u16 Pl[4][16][LP];   // per-wave P bounce (9 KB)

  static const int DMINW[8] = {408, 139, 26, 18, 11, 5, 1, 0};
  static const int DMAXW[8] = {2049, 702, 185, 29, 22, 15, 10, 7};
  static const int DMINS[8] = {412, 143, 30, 22, 15, 9, 5, 2};
  static const int SH[19] = {0,0,0,0,0,0,0,0, 1,1,1,1, 2,2, 3,4,5,6,7};
  static const int SC[19] = {0,1,2,3,4,5,6,7, 0,1,2,3, 0,1, 0,0,0,0,0};
  static const int SN[19] = {8,8,8,8,8,8,8,8, 4,4,4,4, 2,2, 1,1,1,1,1};

  const int slot = blockIdx.x >> 7;
  const int rem = blockIdx.x & 127;
  const int qt = 31 - (rem >> 2);
  const int b = rem & 3;
  const int h = SH[slot], ch = SC[slot], nc = SN[slot];
  const int bh = b * HNUM + h;
  const int q0 = qt * 64;
  const int tid = threadIdx.x;
  const int w = tid >> 6, l = tid & 63, li = l & 15, lg = l >> 4;

  const u16* qrow = qbf + ((size_t)bh * NSEQ + q0 + w * 16 + li) * HDIM;
  u16x8 qf0 = *(const u16x8*)(qrow + lg * 8);
  u16x8 qf1 = *(const u16x8*)(qrow + 32 + lg * 8);

  const bool pure = q0 >= DMINS[h];
  int kv_lo = 0, kv_hi = q0 + 64;
  if (pure) {
    int lo = q0 - DMAXW[h];
    kv_lo = (lo > 0 ? lo : 0) & ~63;
    kv_hi = q0 + 64 - DMINW[h];
  }
  const int t0 = kv_lo >> 6, t1 = (kv_hi - 1) >> 6;
  const int len = t1 - t0 + 1;
  const int ta = t0 + (len * ch) / nc;
  const int tb = t0 + (len * (ch + 1)) / nc - 1;

  const float* btab = bias_tab + h * NSEQ;
  // K fragment base: row (kv0 + 16t + li), cols [8lg, 8lg+8) and +32
  const u16* kfrag = kbf + ((size_t)bh * NSEQ + li) * HDIM + lg * 8;
  // V fragment base: row (16dt + li) of vbfT, cols [kv0+32ks+8lg ...)
  const u16* vfrag = vbfT + ((size_t)bh * HDIM + li) * NSEQ + lg * 8;

  float mrun = -INFINITY, lrun = 0.f;
  f32x4 O[4] = {{0.f,0.f,0.f,0.f},{0.f,0.f,0.f,0.f},
                {0.f,0.f,0.f,0.f},{0.f,0.f,0.f,0.f}};

  for (int tt = ta; tt <= tb; ++tt) {
    const int kv0 = tt << 6;

    // ---- S^T = K Q^T : K fragments direct from global (L2) ----
    f32x4 s[4];
    #pragma unroll
    for (int t = 0; t < 4; ++t) {
      const u16* kp = kfrag + (size_t)(kv0 + t * 16) * HDIM;
      u16x8 a0 = *(const u16x8*)kp;
      u16x8 a1 = *(const u16x8*)(kp + 32);
      f32x4 acc = {0.f, 0.f, 0.f, 0.f};
      acc = mfma_bf16(a0, qf0, acc);
      acc = mfma_bf16(a1, qf1, acc);
      s[t] = acc;
    }

    // ---- bias + causal mask + online softmax (lane owns row i) ----
    const int D0 = (q0 + w * 16 + li) - kv0 - lg * 4;
    float rm = -1e30f;
    #pragma unroll
    for (int t = 0; t < 4; ++t) {
      #pragma unroll
      for (int r = 0; r < 4; ++r) {
        int d = D0 - 16 * t - r;
        float sv = s[t][r];
        sv = (d >= 0) ? (sv + btab[d]) : -1e30f;
        s[t][r] = sv;
        rm = fmaxf(rm, sv);
      }
    }
    rm = fmaxf(rm, __shfl_xor(rm, 16, 64));
    rm = fmaxf(rm, __shfl_xor(rm, 32, 64));
    const float mn = fmaxf(mrun, rm);
    const float f = __expf(mrun - mn);
    mrun = mn;
    float ps = 0.f;
    #pragma unroll
    for (int t = 0; t < 4; ++t) {
      #pragma unroll
      for (int r = 0; r < 4; ++r) {
        float p = __expf(s[t][r] - mn);
        s[t][r] = p;
        ps += p;
      }
    }
    ps += __shfl_xor(ps, 16, 64);
    ps += __shfl_xor(ps, 32, 64);
    lrun = lrun * f + ps;

    // ---- P -> per-wave LDS (transpose to A-frag layout) ----
    #pragma unroll
    for (int t = 0; t < 4; ++t) {
      u16x4 pk;
      pk[0] = f2bf(s[t][0]); pk[1] = f2bf(s[t][1]);
      pk[2] = f2bf(s[t][2]); pk[3] = f2bf(s[t][3]);
      *(u16x4*)&Pl[w][li][t * 16 + lg * 4] = pk;
    }

    // ---- O rescale (broadcast f from lane holding row lg*4+r) ----
    float fr[4];
    #pragma unroll
    for (int r = 0; r < 4; ++r) fr[r] = __shfl(f, lg * 4 + r, 64);
    #pragma unroll
    for (int dt = 0; dt < 4; ++dt) {
      O[dt][0] *= fr[0]; O[dt][1] *= fr[1];
      O[dt][2] *= fr[2]; O[dt][3] *= fr[3];
    }

    // wave-internal fence for Pl (rule #18: lgkmcnt + sched_barrier)
    asm volatile("s_waitcnt lgkmcnt(0)" ::: "memory");
    __builtin_amdgcn_sched_barrier(0);

    // ---- O += P V : V fragments direct from global (L2) ----
    #pragma unroll
    for (int ks = 0; ks < 2; ++ks) {
      u16x8 pA = *(const u16x8*)&Pl[w][li][ks * 32 + lg * 8];
      #pragma unroll
      for (int dt = 0; dt < 4; ++dt) {
        u16x8 vB = *(const u16x8*)(vfrag + (size_t)(dt * 16) * NSEQ +
                                   kv0 + ks * 32);
        O[dt] = mfma_bf16(pA, vB, O[dt]);
      }
    }
    // next iteration overwrites Pl[w] — fence reads before rewrite
    asm volatile("s_waitcnt lgkmcnt(0)" ::: "memory");
    __builtin_amdgcn_sched_barrier(0);
  }

  if (nc == 1) {
    const float gain = if_gain[h];
    float linv[4];
    #pragma unroll
    for (int r = 0; r < 4; ++r)
      linv[r] = gain / __shfl(lrun, lg * 4 + r, 64);
    #pragma unroll
    for (int r = 0; r < 4; ++r) {
      const int i = q0 + w * 16 + lg * 4 + r;
      const size_t base = ((size_t)b * NSEQ + i) * DMODEL + h * HDIM + li;
      #pragma unroll
      for (int dt = 0; dt < 4; ++dt) {
        const float g = bf2f(gate[base + dt * 16]);
        attn_out[base + dt * 16] = f2bf(O[dt][r] * linv[r] * g);
      }
    }
  } else {
    const int sbase = (b * 32 + qt) * NSLOT + slot;   // slot in 0..13 here
    #pragma unroll
    for (int r = 0; r < 4; ++r) {
      const int rl = w * 16 + lg * 4 + r;
      #pragma unroll
      for (int dt = 0; dt < 4; ++dt)
        partO[(size_t)sbase * 4096 + rl * 64 + dt * 16 + li] = f2bf(O[dt][r]);
    }
    if (lg == 0) {
      partM[sbase * 64 + w * 16 + li] = mrun;
      partL[sbase * 64 + w * 16 + li] = lrun;
    }
  }
}

// ---------------------------------------------------------------------------
// Combine split-KV partials: h0 (8 chunks), h1 (4), h2 (2).
// ---------------------------------------------------------------------------
__global__ __launch_bounds__(256) void combine_kernel(
    const u16* __restrict__ partO, const float* __restrict__ partM,
    const float* __restrict__ partL, const float* __restrict__ if_gain,
    const u16* __restrict__ gate, u16* __restrict__ attn_out) {
  const int b = blockIdx.x & 3, qt = blockIdx.x >> 2;
  const int tid = threadIdx.x;
  const int row = tid >> 2, d0 = (tid & 3) << 4;
  static const int HNC[3] = {8, 4, 2};
  static const int HS0[3] = {0, 8, 12};

  #pragma unroll
  for (int hc = 0; hc < 3; ++hc) {
    const int nc = HNC[hc], s0 = HS0[hc];
    const int sbase = (b * 32 + qt) * NSLOT + s0;
    float m[8];
    float M = -INFINITY;
    #pragma unroll
    for (int c = 0; c < 8; ++c) {
      m[c] = (c < nc) ? partM[(sbase + c) * 64 + row] : -INFINITY;
      M = fmaxf(M, m[c]);
    }
    float wch[8];
    float den = 0.f;
    #pragma unroll
    for (int c = 0; c < 8; ++c) {
      wch[c] = (c < nc) ? __expf(m[c] - M) : 0.f;
      if (c < nc) den += wch[c] * partL[(sbase + c) * 64 + row];
    }
    float num[16];
    #pragma unroll
    for (int j = 0; j < 16; ++j) num[j] = 0.f;
    #pragma unroll
    for (int c = 0; c < 8; ++c) {
      if (c < nc) {
        const u16* op = partO + (size_t)(sbase + c) * 4096 + row * 64 + d0;
        u16x8 o0 = *(const u16x8*)op;
        u16x8 o1 = *(const u16x8*)(op + 8);
        #pragma unroll
        for (int j = 0; j < 8; ++j) {
          num[j]     += wch[c] * bf2f(o0[j]);
          num[8 + j] += wch[c] * bf2f(o1[j]);
        }
      }
    }
    const float inv = if_gain[hc] / den;
    const size_t obase =
        ((size_t)b * NSEQ + qt * 64 + row) * DMODEL + hc * HDIM + d0;
    u16x8 g0 = *(const u16x8*)(gate + obase);
    u16x8 g1 = *(const u16x8*)(gate + obase + 8);
    u16x8 r0, r1;
    #pragma unroll
    for (int j = 0; j < 8; ++j) {
      r0[j] = f2bf(num[j] * inv * bf2f(g0[j]));
      r1[j] = f2bf(num[8 + j] * inv * bf2f(g1[j]));
    }
    *(u16x8*)(attn_out + obase) = r0;
    *(u16x8*)(attn_out + obase + 8) = r1;
  }
}

// ---------------------------------------------------------------------------
extern "C" void kernel_launch(void* const* d_in, const int* in_sizes, int n_in,
                              void* d_out, int out_size, void* d_ws,
                              size_t ws_size, hipStream_t stream) {
  const float* x       = (const float*)d_in[0];
  const float* k_delta = (const float*)d_in[1];
  const float* v_delta = (const float*)d_in[2];
  const float* qkv_w   = (const float*)d_in[3];
  const float* qkv_b   = (const float*)d_in[4];
  const float* gate_w  = (const float*)d_in[5];
  const float* gate_b  = (const float*)d_in[6];
  const float* out_w   = (const float*)d_in[7];
  const float* out_b   = (const float*)d_in[8];
  const float* pos_bias = (const float*)d_in[9];
  const float* if_gain  = (const float*)d_in[10];
  float* out = (float*)d_out;
  char* ws = (char*)d_ws;

  // workspace layout (bytes)
  u16*   xbf      = (u16*)(ws + 0);              //  8,388,608 (dead after gemm)
  u16*   qbf      = (u16*)(ws + 8388608);        //  8,388,608
  u16*   kbf      = (u16*)(ws + 16777216);       //  8,388,608
  u16*   vbf      = (u16*)(ws + 25165824);       //  8,388,608 (dead after v-T)
  u16*   vbfT     = (u16*)(ws + 33554432);       //  8,388,608
  u16*   gate_buf = (u16*)(ws + 41943040);       //  8,388,608
  u16*   fused_wt = (u16*)(ws + 50331648);       //  2,097,152
  u16*   out_wt   = (u16*)(ws + 52428800);       //    524,288
  float* bias_tab = (float*)(ws + 52953088);     //     65,536
  u16*   partO = (u16*)(ws + 53018624);          // 14,680,064
  float* partM = (float*)(ws + 67698688);        //    458,752
  float* partL = (float*)(ws + 68157440);        //    458,752
  u16*   attn_buf = vbf;                         // vbf dead after transpose_v

  // prep
  cvt_bf16_kernel<<<dim3(2048), dim3(256), 0, stream>>>(
      x, xbf, BATCH * NSEQ * DMODEL / 8);
  transpose_wall<<<dim3(80, 16), dim3(256), 0, stream>>>(
      qkv_w, gate_w, out_w, fused_wt, out_wt);
  bias_tab_kernel<<<dim3(8), dim3(256), 0, stream>>>(pos_bias, bias_tab);

  // fused qkv+gate GEMM, 128x256 tile, 512 threads, 2 blocks/CU
  gemm_fused<<<dim3(512), dim3(512), 0, stream>>>(
      xbf, fused_wt, qkv_b, gate_b, k_delta, v_delta,
      qbf, kbf, vbf, gate_buf);

  // v -> v^T
  transpose_v_kernel<<<dim3(32, 32), dim3(256), 0, stream>>>(vbf, vbfT);

  // flash attention: split-KV balanced chunks (19 slots), barrier-free KV loop
  attn_kernel<<<dim3(2432), dim3(256), 0, stream>>>(
      qbf, kbf, vbfT, bias_tab, if_gain, gate_buf, attn_buf,
      partO, partM, partL);

  // merge h0/h1/h2 partials
  combine_kernel<<<dim3(128), dim3(256), 0, stream>>>(
      partO, partM, partL, if_gain, gate_buf, attn_buf);

  // final GEMM -> d_out (fp32)
  gemm_out<<<dim3(4, 128), dim3(256), 0, stream>>>(
      attn_buf, out_wt, out_b, out);

  (void)in_sizes; (void)n_in; (void)out_size; (void)ws_size;
}

// Round 16
// 92.572 us; speedup vs baseline: 1.2924x; 1.2924x over previous
//
#include <hip/hip_runtime.h>
#include <cmath>

typedef unsigned short u16;
typedef unsigned short u16x4 __attribute__((ext_vector_type(4)));
typedef unsigned short u16x8 __attribute__((ext_vector_type(8)));
typedef __bf16 bf16x8 __attribute__((ext_vector_type(8)));
typedef float f32x4 __attribute__((ext_vector_type(4)));

#define HNUM 8
#define HDIM 64
#define BATCH 4
#define NSEQ 2048
#define DMODEL 512
#define LP 72    // padded LDS row stride (u16) for attn
#define CPE 264  // padded C-tile row stride (u16) in gemm_fused epilogue
#define NSLOT 14 // split partial slots per (b,qt): h0 x8 + h1 x4 + h2 x2

__device__ __forceinline__ u16 f2bf(float f) {
  unsigned int u = __builtin_bit_cast(unsigned int, f);
  u += 0x7fffu + ((u >> 16) & 1u);          // round-to-nearest-even
  return (u16)(u >> 16);
}

__device__ __forceinline__ float bf2f(u16 v) {
  unsigned int u = ((unsigned int)v) << 16;
  return __builtin_bit_cast(float, u);
}

__device__ __forceinline__ f32x4 mfma_bf16(u16x8 a, u16x8 b, f32x4 c) {
  return __builtin_amdgcn_mfma_f32_16x16x32_bf16(
      __builtin_bit_cast(bf16x8, a), __builtin_bit_cast(bf16x8, b), c, 0, 0, 0);
}

// async global->LDS, 16 B per lane (dest must be wave-uniform base + lane*16)
__device__ __forceinline__ void gload16(u16* lds, const u16* g) {
  __builtin_amdgcn_global_load_lds(
      (const __attribute__((address_space(1))) void*)g,
      (__attribute__((address_space(3))) void*)lds, 16, 0, 0);
}

// chunk-XOR swizzle (rounds 10-14 verified): linear LDS dest, inverse-swizzled
// global source; read with the same XOR. 32-col (BK=32) tiles.
__device__ __forceinline__ int swz_off(int row, int lg) {
  return row * 32 + ((lg ^ ((row >> 1) & 3)) << 3);
}

// 256-thread staging (gemm_out)
template <int ROWS>
__device__ __forceinline__ void stage_tile(u16* lds, const u16* g, int tid) {
  #pragma unroll
  for (int i = 0; i < ROWS / 64; ++i) {
    const int t = i * 256 + tid;
    const int row = t >> 2;
    const int ch = (t & 3) ^ ((row >> 1) & 3);
    gload16(lds + t * 8, g + (size_t)row * DMODEL + ch * 8);
  }
}

// 512-thread staging of A(128x32) + B(256x32), 3 loads/thread
__device__ __forceinline__ void stageAB(u16* ldsA, u16* ldsB, const u16* gA,
                                        const u16* gB, int tid) {
  {
    const int s = tid;                       // A: 512 loads
    const int row = s >> 2;
    const int ch = (s & 3) ^ ((row >> 1) & 3);
    gload16(ldsA + s * 8, gA + (size_t)row * DMODEL + ch * 8);
  }
  #pragma unroll
  for (int i = 0; i < 2; ++i) {              // B: 1024 loads
    const int s = i * 512 + tid;
    const int row = s >> 2;
    const int ch = (s & 3) ^ ((row >> 1) & 3);
    gload16(ldsB + s * 8, gB + (size_t)row * DMODEL + ch * 8);
  }
}

// ---------------------------------------------------------------------------
// Prep: fp32 -> bf16 convert (x), 8 elems/thread
// ---------------------------------------------------------------------------
__global__ __launch_bounds__(256) void cvt_bf16_kernel(
    const float* __restrict__ in, u16* __restrict__ out, int n8) {
  int i = blockIdx.x * 256 + threadIdx.x;
  if (i >= n8) return;
  const float4 f0 = *(const float4*)(in + i * 8);
  const float4 f1 = *(const float4*)(in + i * 8 + 4);
  u16x8 pk;
  pk[0] = f2bf(f0.x); pk[1] = f2bf(f0.y); pk[2] = f2bf(f0.z); pk[3] = f2bf(f0.w);
  pk[4] = f2bf(f1.x); pk[5] = f2bf(f1.y); pk[6] = f2bf(f1.z); pk[7] = f2bf(f1.w);
  *(u16x8*)(out + i * 8) = pk;
}

// ---------------------------------------------------------------------------
// Prep: all three weight transposes in ONE kernel.
// blockIdx.x: 0-47 qkv_w (N=1536) | 48-63 gate_w | 64-79 out_w.
// ---------------------------------------------------------------------------
__global__ __launch_bounds__(256) void transpose_wall(
    const float* __restrict__ qkv_w, const float* __restrict__ gate_w,
    const float* __restrict__ out_w, u16* __restrict__ fused_wt,
    u16* __restrict__ out_wt) {
  __shared__ float tile[32][33];
  const int bx = blockIdx.x;
  const float* W;
  u16* Wt;
  int N, nb;
  if (bx < 48)      { W = qkv_w;  Wt = fused_wt;                     N = 1536; nb = bx; }
  else if (bx < 64) { W = gate_w; Wt = fused_wt + (size_t)1536 * 512; N = 512;  nb = bx - 48; }
  else              { W = out_w;  Wt = out_wt;                       N = 512;  nb = bx - 64; }
  const int n0 = nb * 32, k0 = blockIdx.y * 32;
  const int tx = threadIdx.x & 31, ty = threadIdx.x >> 5;
  #pragma unroll
  for (int yy = ty; yy < 32; yy += 8)
    tile[yy][tx] = W[(size_t)(k0 + yy) * N + n0 + tx];
  __syncthreads();
  #pragma unroll
  for (int yy = ty; yy < 32; yy += 8)
    Wt[(size_t)(n0 + yy) * DMODEL + k0 + tx] = f2bf(tile[tx][yy]);
}

// ---------------------------------------------------------------------------
// Prep: vbf[b,h,n,d] -> vbfT[b,h,d,n] (64x64 LDS tile transpose)
// ---------------------------------------------------------------------------
__global__ __launch_bounds__(256) void transpose_v_kernel(
    const u16* __restrict__ v, u16* __restrict__ vT) {
  __shared__ u16 t[64][LP];
  const int n0 = blockIdx.x * 64;
  const size_t bh = blockIdx.y;
  const int r = threadIdx.x >> 2, c0 = (threadIdx.x & 3) << 4;
  const u16* src = v + (bh * NSEQ + n0 + r) * HDIM + c0;
  u16x8 a0 = *(const u16x8*)src;
  u16x8 a1 = *(const u16x8*)(src + 8);
  #pragma unroll
  for (int j = 0; j < 8; ++j) {
    t[c0 + j][r] = a0[j];
    t[c0 + 8 + j][r] = a1[j];
  }
  __syncthreads();
  u16x8 o0 = *(const u16x8*)&t[r][c0];
  u16x8 o1 = *(const u16x8*)&t[r][c0 + 8];
  u16* dst = vT + (bh * HDIM + r) * NSEQ + n0 + c0;
  *(u16x8*)dst = o0;
  *(u16x8*)(dst + 8) = o1;
}

// ---------------------------------------------------------------------------
// Bias table: tab[h][d] = in_band(bucket(d),h) ? pos_bias[bucket(d)][h] : -100
// ---------------------------------------------------------------------------
__global__ __launch_bounds__(256) void bias_tab_kernel(
    const float* __restrict__ pos_bias, float* __restrict__ tab) {
  int d = blockIdx.x * 256 + threadIdx.x;   // 0..2047
  if (d >= NSEQ) return;
  int bkt;
  if (d < 28) {
    bkt = d;
  } else {
    double t = log((double)d / 28.0) / log(2048.0 / 28.0) * 16.0;
    int ti = 28 + (int)t;
    bkt = ti < 43 ? ti : 43;
  }
  const int lo[8] = {38, 34, 28, 20, 13, 7, 3, 0};
  const int hi[8] = {44, 40, 35, 28, 21, 14, 9, 6};
  #pragma unroll
  for (int h = 0; h < HNUM; ++h) {
    bool inb = (bkt >= lo[h]) && (bkt < hi[h]);
    tab[h * NSEQ + d] = inb ? pos_bias[bkt * HNUM + h] : -100.0f;
  }
}

// ---------------------------------------------------------------------------
// Fused qkv+gate GEMM: 128x256 tile, BK=32, 512 threads, 2 blocks/CU,
// single-barrier 3-deep counted-vmcnt loop (round-14 verified).
// ---------------------------------------------------------------------------
__global__ __launch_bounds__(512, 4) void gemm_fused(
    const u16* __restrict__ Abf, const u16* __restrict__ Wt,
    const float* __restrict__ qkv_b, const float* __restrict__ gate_b,
    const float* __restrict__ kdelta, const float* __restrict__ vdelta,
    u16* __restrict__ qbf, u16* __restrict__ kbf, u16* __restrict__ vbf,
    u16* __restrict__ gate) {
  __shared__ __align__(16) u16 S[36864];   // 72 KB
  u16* SA3[3] = {S, S + 4096, S + 8192};
  u16* SB3[3] = {S + 12288, S + 20480, S + 28672};

  // XCD band map: XCD x owns m-tiles 8x..8x+7 (1MB A) x all n (2MB W)
  const int bid = blockIdx.x;
  const int xcd = bid & 7, loc = bid >> 3;
  const int m0 = (xcd * 8 + (loc & 7)) * 128;
  const int n0 = (loc >> 3) * 256;

  const int tid = threadIdx.x;
  const int w = tid >> 6, l = tid & 63, li = l & 15, lg = l >> 4;
  const int wm = w >> 2, wn = w & 3;

  f32x4 acc[4][4];
  #pragma unroll
  for (int i = 0; i < 4; ++i)
    #pragma unroll
    for (int j = 0; j < 4; ++j) acc[i][j] = f32x4{0.f, 0.f, 0.f, 0.f};

  const u16* Ab = Abf + (size_t)m0 * DMODEL;
  const u16* Bb = Wt + (size_t)n0 * DMODEL;

  stageAB(SA3[0], SB3[0], Ab, Bb, tid);
  stageAB(SA3[1], SB3[1], Ab + 32, Bb + 32, tid);

  #pragma unroll
  for (int kt = 0; kt < 16; ++kt) {
    if (kt <= 14) asm volatile("s_waitcnt vmcnt(3)" ::: "memory");
    else          asm volatile("s_waitcnt vmcnt(0)" ::: "memory");
    __builtin_amdgcn_s_barrier();        // all waves done reading tile kt-1
    __builtin_amdgcn_sched_barrier(0);
    if (kt + 2 < 16)                     // safe: buffer (kt+2)%3 = (kt-1)%3
      stageAB(SA3[(kt + 2) % 3], SB3[(kt + 2) % 3],
              Ab + (kt + 2) * 32, Bb + (kt + 2) * 32, tid);
    const u16* Asb = SA3[kt % 3];
    const u16* Bsb = SB3[kt % 3];
    u16x8 af[4], bfr[4];
    #pragma unroll
    for (int mt = 0; mt < 4; ++mt)
      af[mt] = *(const u16x8*)&Asb[swz_off(wm * 64 + mt * 16 + li, lg)];
    #pragma unroll
    for (int nt = 0; nt < 4; ++nt)
      bfr[nt] = *(const u16x8*)&Bsb[swz_off(wn * 64 + nt * 16 + li, lg)];
    asm volatile("s_waitcnt lgkmcnt(0)" ::: "memory");
    __builtin_amdgcn_sched_barrier(0);
    #pragma unroll
    for (int mt = 0; mt < 4; ++mt)
      #pragma unroll
      for (int nt = 0; nt < 4; ++nt)
        acc[mt][nt] = mfma_bf16(af[mt], bfr[nt], acc[mt][nt]);
  }
  __syncthreads();                       // all reads done before S reuse

  // ---- epilogue: acc+bias -> padded LDS C-tile (128x256, stride CPE) ----
  u16* Ct = S;
  const int seg = n0 >> 9;                   // 0=q 1=k 2=v 3=gate (uniform)
  const int nin = n0 & 511;                  // 0 or 256
  #pragma unroll
  for (int nt = 0; nt < 4; ++nt) {
    const int col = wn * 64 + nt * 16 + li;
    const int colg = n0 + col;
    const float bv = (seg < 3) ? qkv_b[colg] : gate_b[colg & 511];
    #pragma unroll
    for (int mt = 0; mt < 4; ++mt) {
      const int row = wm * 64 + mt * 16 + lg * 4;
      #pragma unroll
      for (int r = 0; r < 4; ++r)
        Ct[(row + r) * CPE + col] = f2bf(acc[mt][nt][r] + bv);
    }
  }
  __syncthreads();

  // ---- packed coalesced writes from LDS (8 u16x8 per thread) ----
  #pragma unroll
  for (int p = 0; p < 8; ++p) {
    const int idx = p * 512 + tid;
    const int row = idx >> 5, ccol = (idx & 31) * 8;
    const int rg = m0 + row;
    const int bb = rg >> 11, n = rg & 2047;
    u16x8 cv = *(const u16x8*)&Ct[row * CPE + ccol];
    const int cws = nin + ccol;              // col within 512-wide segment
    if (seg == 3) {
      u16x8 o;
      #pragma unroll
      for (int j = 0; j < 8; ++j)
        o[j] = f2bf(1.f / (1.f + __expf(-bf2f(cv[j]))));
      *(u16x8*)&gate[(size_t)rg * DMODEL + cws] = o;
    } else {
      const int hh = cws >> 6, hd = cws & 63;
      const size_t hidx = (((size_t)bb * HNUM + hh) * NSEQ + n) * HDIM + hd;
      if (seg == 0) {
        u16x8 o;
        #pragma unroll
        for (int j = 0; j < 8; ++j) o[j] = f2bf(bf2f(cv[j]) * 0.125f);
        *(u16x8*)&qbf[hidx] = o;
      } else {
        const float* dp = (seg == 1 ? kdelta : vdelta) + hidx;
        float4 d0 = *(const float4*)dp;
        float4 d1 = *(const float4*)(dp + 4);
        u16x8 o;
        o[0] = f2bf(bf2f(cv[0]) + d0.x); o[1] = f2bf(bf2f(cv[1]) + d0.y);
        o[2] = f2bf(bf2f(cv[2]) + d0.z); o[3] = f2bf(bf2f(cv[3]) + d0.w);
        o[4] = f2bf(bf2f(cv[4]) + d1.x); o[5] = f2bf(bf2f(cv[5]) + d1.y);
        o[6] = f2bf(bf2f(cv[6]) + d1.z); o[7] = f2bf(bf2f(cv[7]) + d1.w);
        *(u16x8*)&((seg == 1) ? kbf : vbf)[hidx] = o;
      }
    }
  }
}

// ---------------------------------------------------------------------------
// Out GEMM: 64x128 tile, BK=32, single-barrier 3-deep loop (verified).
// ---------------------------------------------------------------------------
__global__ __launch_bounds__(256) void gemm_out(
    const u16* __restrict__ Abf, const u16* __restrict__ Wt,
    const float* __restrict__ bias, float* __restrict__ outf) {
  __shared__ __align__(16) u16 As[3][64 * 32];
  __shared__ __align__(16) u16 Bs[3][128 * 32];

  const int m0 = blockIdx.y * 64, n0 = blockIdx.x * 128;
  const int tid = threadIdx.x;
  const int w = tid >> 6, l = tid & 63, li = l & 15, lg = l >> 4;
  const int wr = w >> 1, wc = w & 1;

  f32x4 acc[2][4];
  #pragma unroll
  for (int i = 0; i < 2; ++i)
    #pragma unroll
    for (int j = 0; j < 4; ++j) acc[i][j] = f32x4{0.f, 0.f, 0.f, 0.f};

  const u16* Ab = Abf + (size_t)m0 * DMODEL;
  const u16* Bb = Wt + (size_t)n0 * DMODEL;

  stage_tile<64>(As[0], Ab, tid);
  stage_tile<128>(Bs[0], Bb, tid);
  stage_tile<64>(As[1], Ab + 32, tid);
  stage_tile<128>(Bs[1], Bb + 32, tid);

  #pragma unroll
  for (int kt = 0; kt < 16; ++kt) {
    if (kt <= 14) asm volatile("s_waitcnt vmcnt(3)" ::: "memory");
    else          asm volatile("s_waitcnt vmcnt(0)" ::: "memory");
    __builtin_amdgcn_s_barrier();
    __builtin_amdgcn_sched_barrier(0);
    if (kt + 2 < 16) {
      stage_tile<64>(As[(kt + 2) % 3], Ab + (kt + 2) * 32, tid);
      stage_tile<128>(Bs[(kt + 2) % 3], Bb + (kt + 2) * 32, tid);
    }
    const u16* Asb = As[kt % 3];
    const u16* Bsb = Bs[kt % 3];
    u16x8 af[2], bfr[4];
    #pragma unroll
    for (int mt = 0; mt < 2; ++mt)
      af[mt] = *(const u16x8*)&Asb[swz_off(wr * 32 + mt * 16 + li, lg)];
    #pragma unroll
    for (int nt = 0; nt < 4; ++nt)
      bfr[nt] = *(const u16x8*)&Bsb[swz_off(wc * 64 + nt * 16 + li, lg)];
    asm volatile("s_waitcnt lgkmcnt(0)" ::: "memory");
    __builtin_amdgcn_sched_barrier(0);
    #pragma unroll
    for (int mt = 0; mt < 2; ++mt)
      #pragma unroll
      for (int nt = 0; nt < 4; ++nt)
        acc[mt][nt] = mfma_bf16(af[mt], bfr[nt], acc[mt][nt]);
  }

  #pragma unroll
  for (int nt = 0; nt < 4; ++nt) {
    const int colg = n0 + wc * 64 + nt * 16 + li;
    const float bv = bias[colg];
    #pragma unroll
    for (int mt = 0; mt < 2; ++mt) {
      #pragma unroll
      for (int r = 0; r < 4; ++r) {
        const int rowg = m0 + wr * 32 + mt * 16 + lg * 4 + r;
        outf[(size_t)rowg * DMODEL + colg] = acc[mt][nt][r] + bv;
      }
    }
  }
}

// ---------------------------------------------------------------------------
// Flash attention (round-14 verified staged body + T14 async-STAGE split):
// prologue-load K/V tile into regs; per tile: regs->LDS, barrier, ISSUE next
// tile's global loads (latency hides under QK^T+softmax+PV), compute.
// Slots: h0 x8 (0-7), h1 x4 (8-11), h2 x2 (12-13), h3..h7 direct (14-18).
// ---------------------------------------------------------------------------
__global__ __launch_bounds__(256) void attn_kernel(
    const u16* __restrict__ qbf, const u16* __restrict__ kbf,
    const u16* __restrict__ vbfT, const float* __restrict__ bias_tab,
    const float* __restrict__ if_gain, const u16* __restrict__ gate,
    u16* __restrict__ attn_out, u16* __restrict__ partO,
    float* __restrict__ partM, float* __restrict__ partL) {
  __shared__ __align__(16) u16 Ks[64][LP];   // [kv][hd]
  __shared__ __align__(16) u16 Vt[64][LP];   // [hd][kv]
  __shared__ __align__(16) u16 Pl[4][16][LP];

  static const int DMINW[8] = {408, 139, 26, 18, 11, 5, 1, 0};
  static const int DMAXW[8] = {2049, 702, 185, 29, 22, 15, 10, 7};
  static const int DMINS[8] = {412, 143, 30, 22, 15, 9, 5, 2};
  static const int SH[19] = {0,0,0,0,0,0,0,0, 1,1,1,1, 2,2, 3,4,5,6,7};
  static const int SC[19] = {0,1,2,3,4,5,6,7, 0,1,2,3, 0,1, 0,0,0,0,0};
  static const int SN[19] = {8,8,8,8,8,8,8,8, 4,4,4,4, 2,2, 1,1,1,1,1};

  const int slot = blockIdx.x >> 7;
  const int rem = blockIdx.x & 127;
  const int qt = 31 - (rem >> 2);
  const int b = rem & 3;
  const int h = SH[slot], ch = SC[slot], nc = SN[slot];
  const int bh = b * HNUM + h;
  const int q0 = qt * 64;
  const int tid = threadIdx.x;
  const int w = tid >> 6, l = tid & 63, li = l & 15, lg = l >> 4;

  const u16* qrow = qbf + ((size_t)bh * NSEQ + q0 + w * 16 + li) * HDIM;
  u16x8 qf0 = *(const u16x8*)(qrow + lg * 8);
  u16x8 qf1 = *(const u16x8*)(qrow + 32 + lg * 8);

  const bool pure = q0 >= DMINS[h];
  int kv_lo = 0, kv_hi = q0 + 64;
  if (pure) {
    int lo = q0 - DMAXW[h];
    kv_lo = (lo > 0 ? lo : 0) & ~63;
    kv_hi = q0 + 64 - DMINW[h];
  }
  const int t0 = kv_lo >> 6, t1 = (kv_hi - 1) >> 6;
  const int len = t1 - t0 + 1;
  const int ta = t0 + (len * ch) / nc;
  const int tb = t0 + (len * (ch + 1)) / nc - 1;

  const int srow = tid >> 2;
  const int scb = (tid & 3) << 4;
  const float* btab = bias_tab + h * NSEQ;

  // T14 prologue: load tile ta into registers
  u16x8 kr0, kr1, vr0, vr1;
  {
    const int kv0 = ta << 6;
    const size_t kbase = ((size_t)bh * NSEQ + kv0 + srow) * HDIM + scb;
    kr0 = *(const u16x8*)(kbf + kbase);
    kr1 = *(const u16x8*)(kbf + kbase + 8);
    const size_t vbase = ((size_t)bh * HDIM + srow) * NSEQ + kv0 + scb;
    vr0 = *(const u16x8*)(vbfT + vbase);
    vr1 = *(const u16x8*)(vbfT + vbase + 8);
  }

  float mrun = -INFINITY, lrun = 0.f;
  f32x4 O[4] = {{0.f,0.f,0.f,0.f},{0.f,0.f,0.f,0.f},
                {0.f,0.f,0.f,0.f},{0.f,0.f,0.f,0.f}};

  for (int tt = ta; tt <= tb; ++tt) {
    const int kv0 = tt << 6;
    // ---- write staged regs -> LDS ----
    *(u16x8*)&Ks[srow][scb] = kr0;
    *(u16x8*)&Ks[srow][scb + 8] = kr1;
    *(u16x8*)&Vt[srow][scb] = vr0;
    *(u16x8*)&Vt[srow][scb + 8] = vr1;
    __syncthreads();

    // ---- T14: issue NEXT tile's global loads (consumed next iteration) ----
    if (tt < tb) {
      const int kv1 = (tt + 1) << 6;
      const size_t kbase = ((size_t)bh * NSEQ + kv1 + srow) * HDIM + scb;
      kr0 = *(const u16x8*)(kbf + kbase);
      kr1 = *(const u16x8*)(kbf + kbase + 8);
      const size_t vbase = ((size_t)bh * HDIM + srow) * NSEQ + kv1 + scb;
      vr0 = *(const u16x8*)(vbfT + vbase);
      vr1 = *(const u16x8*)(vbfT + vbase + 8);
    }

    // ---- S^T = K Q^T : 4 j-tiles x (K=64 -> 2 mfma) ----
    f32x4 s[4];
    #pragma unroll
    for (int t = 0; t < 4; ++t) {
      u16x8 a0 = *(const u16x8*)&Ks[t * 16 + li][lg * 8];
      u16x8 a1 = *(const u16x8*)&Ks[t * 16 + li][32 + lg * 8];
      f32x4 acc = {0.f, 0.f, 0.f, 0.f};
      acc = mfma_bf16(a0, qf0, acc);
      acc = mfma_bf16(a1, qf1, acc);
      s[t] = acc;
    }

    const int D0 = (q0 + w * 16 + li) - kv0 - lg * 4;
    float rm = -1e30f;
    #pragma unroll
    for (int t = 0; t < 4; ++t) {
      #pragma unroll
      for (int r = 0; r < 4; ++r) {
        int d = D0 - 16 * t - r;
        float sv = s[t][r];
        sv = (d >= 0) ? (sv + btab[d]) : -1e30f;
        s[t][r] = sv;
        rm = fmaxf(rm, sv);
      }
    }
    rm = fmaxf(rm, __shfl_xor(rm, 16, 64));
    rm = fmaxf(rm, __shfl_xor(rm, 32, 64));
    const float mn = fmaxf(mrun, rm);
    const float f = __expf(mrun - mn);
    mrun = mn;
    float ps = 0.f;
    #pragma unroll
    for (int t = 0; t < 4; ++t) {
      #pragma unroll
      for (int r = 0; r < 4; ++r) {
        float p = __expf(s[t][r] - mn);
        s[t][r] = p;
        ps += p;
      }
    }
    ps += __shfl_xor(ps, 16, 64);
    ps += __shfl_xor(ps, 32, 64);
    lrun = lrun * f + ps;

    #pragma unroll
    for (int t = 0; t < 4; ++t) {
      u16x4 pk;
      pk[0] = f2bf(s[t][0]); pk[1] = f2bf(s[t][1]);
      pk[2] = f2bf(s[t][2]); pk[3] = f2bf(s[t][3]);
      *(u16x4*)&Pl[w][li][t * 16 + lg * 4] = pk;
    }

    float fr[4];
    #pragma unroll
    for (int r = 0; r < 4; ++r) fr[r] = __shfl(f, lg * 4 + r, 64);
    #pragma unroll
    for (int dt = 0; dt < 4; ++dt) {
      O[dt][0] *= fr[0]; O[dt][1] *= fr[1];
      O[dt][2] *= fr[2]; O[dt][3] *= fr[3];
    }
    __syncthreads();

    #pragma unroll
    for (int ks = 0; ks < 2; ++ks) {
      u16x8 pA = *(const u16x8*)&Pl[w][li][ks * 32 + lg * 8];
      #pragma unroll
      for (int dt = 0; dt < 4; ++dt) {
        u16x8 vB = *(const u16x8*)&Vt[dt * 16 + li][ks * 32 + lg * 8];
        O[dt] = mfma_bf16(pA, vB, O[dt]);
      }
    }
    __syncthreads();
  }

  if (nc == 1) {
    const float gain = if_gain[h];
    float linv[4];
    #pragma unroll
    for (int r = 0; r < 4; ++r)
      linv[r] = gain / __shfl(lrun, lg * 4 + r, 64);
    #pragma unroll
    for (int r = 0; r < 4; ++r) {
      const int i = q0 + w * 16 + lg * 4 + r;
      const size_t base = ((size_t)b * NSEQ + i) * DMODEL + h * HDIM + li;
      #pragma unroll
      for (int dt = 0; dt < 4; ++dt) {
        const float g = bf2f(gate[base + dt * 16]);
        attn_out[base + dt * 16] = f2bf(O[dt][r] * linv[r] * g);
      }
    }
  } else {
    const int sbase = (b * 32 + qt) * NSLOT + slot;   // slot in 0..13 here
    #pragma unroll
    for (int r = 0; r < 4; ++r) {
      const int rl = w * 16 + lg * 4 + r;
      #pragma unroll
      for (int dt = 0; dt < 4; ++dt)
        partO[(size_t)sbase * 4096 + rl * 64 + dt * 16 + li] = f2bf(O[dt][r]);
    }
    if (lg == 0) {
      partM[sbase * 64 + w * 16 + li] = mrun;
      partL[sbase * 64 + w * 16 + li] = lrun;
    }
  }
}

// ---------------------------------------------------------------------------
// Combine split-KV partials: h0 (8 chunks), h1 (4), h2 (2).
// ---------------------------------------------------------------------------
__global__ __launch_bounds__(256) void combine_kernel(
    const u16* __restrict__ partO, const float* __restrict__ partM,
    const float* __restrict__ partL, const float* __restrict__ if_gain,
    const u16* __restrict__ gate, u16* __restrict__ attn_out) {
  const int b = blockIdx.x & 3, qt = blockIdx.x >> 2;
  const int tid = threadIdx.x;
  const int row = tid >> 2, d0 = (tid & 3) << 4;
  static const int HNC[3] = {8, 4, 2};
  static const int HS0[3] = {0, 8, 12};

  #pragma unroll
  for (int hc = 0; hc < 3; ++hc) {
    const int nc = HNC[hc], s0 = HS0[hc];
    const int sbase = (b * 32 + qt) * NSLOT + s0;
    float m[8];
    float M = -INFINITY;
    #pragma unroll
    for (int c = 0; c < 8; ++c) {
      m[c] = (c < nc) ? partM[(sbase + c) * 64 + row] : -INFINITY;
      M = fmaxf(M, m[c]);
    }
    float wch[8];
    float den = 0.f;
    #pragma unroll
    for (int c = 0; c < 8; ++c) {
      wch[c] = (c < nc) ? __expf(m[c] - M) : 0.f;
      if (c < nc) den += wch[c] * partL[(sbase + c) * 64 + row];
    }
    float num[16];
    #pragma unroll
    for (int j = 0; j < 16; ++j) num[j] = 0.f;
    #pragma unroll
    for (int c = 0; c < 8; ++c) {
      if (c < nc) {
        const u16* op = partO + (size_t)(sbase + c) * 4096 + row * 64 + d0;
        u16x8 o0 = *(const u16x8*)op;
        u16x8 o1 = *(const u16x8*)(op + 8);
        #pragma unroll
        for (int j = 0; j < 8; ++j) {
          num[j]     += wch[c] * bf2f(o0[j]);
          num[8 + j] += wch[c] * bf2f(o1[j]);
        }
      }
    }
    const float inv = if_gain[hc] / den;
    const size_t obase =
        ((size_t)b * NSEQ + qt * 64 + row) * DMODEL + hc * HDIM + d0;
    u16x8 g0 = *(const u16x8*)(gate + obase);
    u16x8 g1 = *(const u16x8*)(gate + obase + 8);
    u16x8 r0, r1;
    #pragma unroll
    for (int j = 0; j < 8; ++j) {
      r0[j] = f2bf(num[j] * inv * bf2f(g0[j]));
      r1[j] = f2bf(num[8 + j] * inv * bf2f(g1[j]));
    }
    *(u16x8*)(attn_out + obase) = r0;
    *(u16x8*)(attn_out + obase + 8) = r1;
  }
}

// ---------------------------------------------------------------------------
extern "C" void kernel_launch(void* const* d_in, const int* in_sizes, int n_in,
                              void* d_out, int out_size, void* d_ws,
                              size_t ws_size, hipStream_t stream) {
  const float* x       = (const float*)d_in[0];
  const float* k_delta = (const float*)d_in[1];
  const float* v_delta = (const float*)d_in[2];
  const float* qkv_w   = (const float*)d_in[3];
  const float* qkv_b   = (const float*)d_in[4];
  const float* gate_w  = (const float*)d_in[5];
  const float* gate_b  = (const float*)d_in[6];
  const float* out_w   = (const float*)d_in[7];
  const float* out_b   = (const float*)d_in[8];
  const float* pos_bias = (const float*)d_in[9];
  const float* if_gain  = (const float*)d_in[10];
  float* out = (float*)d_out;
  char* ws = (char*)d_ws;

  // workspace layout (bytes)
  u16*   xbf      = (u16*)(ws + 0);              //  8,388,608 (dead after gemm)
  u16*   qbf      = (u16*)(ws + 8388608);        //  8,388,608
  u16*   kbf      = (u16*)(ws + 16777216);       //  8,388,608
  u16*   vbf      = (u16*)(ws + 25165824);       //  8,388,608 (dead after v-T)
  u16*   vbfT     = (u16*)(ws + 33554432);       //  8,388,608
  u16*   gate_buf = (u16*)(ws + 41943040);       //  8,388,608
  u16*   fused_wt = (u16*)(ws + 50331648);       //  2,097,152
  u16*   out_wt   = (u16*)(ws + 52428800);       //    524,288
  float* bias_tab = (float*)(ws + 52953088);     //     65,536
  u16*   partO = (u16*)(ws + 53018624);          // 14,680,064
  float* partM = (float*)(ws + 67698688);        //    458,752
  float* partL = (float*)(ws + 68157440);        //    458,752
  u16*   attn_buf = vbf;                         // vbf dead after transpose_v

  // prep
  cvt_bf16_kernel<<<dim3(2048), dim3(256), 0, stream>>>(
      x, xbf, BATCH * NSEQ * DMODEL / 8);
  transpose_wall<<<dim3(80, 16), dim3(256), 0, stream>>>(
      qkv_w, gate_w, out_w, fused_wt, out_wt);
  bias_tab_kernel<<<dim3(8), dim3(256), 0, stream>>>(pos_bias, bias_tab);

  // fused qkv+gate GEMM, 128x256 tile, 512 threads, 2 blocks/CU
  gemm_fused<<<dim3(512), dim3(512), 0, stream>>>(
      xbf, fused_wt, qkv_b, gate_b, k_delta, v_delta,
      qbf, kbf, vbf, gate_buf);

  // v -> v^T
  transpose_v_kernel<<<dim3(32, 32), dim3(256), 0, stream>>>(vbf, vbfT);

  // flash attention: split-KV balanced chunks (19 slots), T14 staged
  attn_kernel<<<dim3(2432), dim3(256), 0, stream>>>(
      qbf, kbf, vbfT, bias_tab, if_gain, gate_buf, attn_buf,
      partO, partM, partL);

  // merge h0/h1/h2 partials
  combine_kernel<<<dim3(128), dim3(256), 0, stream>>>(
      partO, partM, partL, if_gain, gate_buf, attn_buf);

  // final GEMM -> d_out (fp32)
  gemm_out<<<dim3(4, 128), dim3(256), 0, stream>>>(
      attn_buf, out_wt, out_b, out);

  (void)in_sizes; (void)n_in; (void)out_size; (void)ws_size;
}

// Round 17
// 87.023 us; speedup vs baseline: 1.3748x; 1.0638x over previous
//
#include <hip/hip_runtime.h>
#include <cmath>

typedef unsigned short u16;
typedef unsigned short u16x4 __attribute__((ext_vector_type(4)));
typedef unsigned short u16x8 __attribute__((ext_vector_type(8)));
typedef __bf16 bf16x8 __attribute__((ext_vector_type(8)));
typedef float f32x4 __attribute__((ext_vector_type(4)));

#define HNUM 8
#define HDIM 64
#define BATCH 4
#define NSEQ 2048
#define DMODEL 512
#define LP 72    // padded LDS row stride (u16) for attn
#define CPE 264  // padded C-tile row stride (u16) in gemm_fused epilogue
#define NSLOT 14 // split partial slots per (b,qt): h0 x8 + h1 x4 + h2 x2

__device__ __forceinline__ u16 f2bf(float f) {
  unsigned int u = __builtin_bit_cast(unsigned int, f);
  u += 0x7fffu + ((u >> 16) & 1u);          // round-to-nearest-even
  return (u16)(u >> 16);
}

__device__ __forceinline__ float bf2f(u16 v) {
  unsigned int u = ((unsigned int)v) << 16;
  return __builtin_bit_cast(float, u);
}

__device__ __forceinline__ f32x4 mfma_bf16(u16x8 a, u16x8 b, f32x4 c) {
  return __builtin_amdgcn_mfma_f32_16x16x32_bf16(
      __builtin_bit_cast(bf16x8, a), __builtin_bit_cast(bf16x8, b), c, 0, 0, 0);
}

// async global->LDS, 16 B per lane (dest must be wave-uniform base + lane*16)
__device__ __forceinline__ void gload16(u16* lds, const u16* g) {
  __builtin_amdgcn_global_load_lds(
      (const __attribute__((address_space(1))) void*)g,
      (__attribute__((address_space(3))) void*)lds, 16, 0, 0);
}

// chunk-XOR swizzle (rounds 10-16 verified): linear LDS dest, inverse-swizzled
// global source; read with the same XOR. 32-col (BK=32) tiles.
__device__ __forceinline__ int swz_off(int row, int lg) {
  return row * 32 + ((lg ^ ((row >> 1) & 3)) << 3);
}

// 256-thread staging (gemm_out)
template <int ROWS>
__device__ __forceinline__ void stage_tile(u16* lds, const u16* g, int tid) {
  #pragma unroll
  for (int i = 0; i < ROWS / 64; ++i) {
    const int t = i * 256 + tid;
    const int row = t >> 2;
    const int ch = (t & 3) ^ ((row >> 1) & 3);
    gload16(lds + t * 8, g + (size_t)row * DMODEL + ch * 8);
  }
}

// 512-thread staging of A(128x32) + B(256x32), 3 loads/thread
__device__ __forceinline__ void stageAB(u16* ldsA, u16* ldsB, const u16* gA,
                                        const u16* gB, int tid) {
  {
    const int s = tid;                       // A: 512 loads
    const int row = s >> 2;
    const int ch = (s & 3) ^ ((row >> 1) & 3);
    gload16(ldsA + s * 8, gA + (size_t)row * DMODEL + ch * 8);
  }
  #pragma unroll
  for (int i = 0; i < 2; ++i) {              // B: 1024 loads
    const int s = i * 512 + tid;
    const int row = s >> 2;
    const int ch = (s & 3) ^ ((row >> 1) & 3);
    gload16(ldsB + s * 8, gB + (size_t)row * DMODEL + ch * 8);
  }
}

// ---------------------------------------------------------------------------
// Merged prep kernel: blockIdx.x decodes role.
//   [0, 2048)        : x fp32 -> bf16 (8 elems/thread)
//   [2048, 3328)     : weight transposes (80 n-blocks x 16 k-blocks)
//   [3328, 3336)     : bias table
// ---------------------------------------------------------------------------
__global__ __launch_bounds__(256) void prep_kernel(
    const float* __restrict__ x, const float* __restrict__ qkv_w,
    const float* __restrict__ gate_w, const float* __restrict__ out_w,
    const float* __restrict__ pos_bias, u16* __restrict__ xbf,
    u16* __restrict__ fused_wt, u16* __restrict__ out_wt,
    float* __restrict__ bias_tab) {
  __shared__ float tile[32][33];
  const int bx = blockIdx.x;
  const int tid = threadIdx.x;

  if (bx < 2048) {                       // ---- cvt x -> bf16 ----
    const int i = bx * 256 + tid;        // n8 = 524288 exactly
    const float4 f0 = *(const float4*)(x + (size_t)i * 8);
    const float4 f1 = *(const float4*)(x + (size_t)i * 8 + 4);
    u16x8 pk;
    pk[0] = f2bf(f0.x); pk[1] = f2bf(f0.y); pk[2] = f2bf(f0.z); pk[3] = f2bf(f0.w);
    pk[4] = f2bf(f1.x); pk[5] = f2bf(f1.y); pk[6] = f2bf(f1.z); pk[7] = f2bf(f1.w);
    *(u16x8*)(xbf + (size_t)i * 8) = pk;
  } else if (bx < 3328) {                // ---- weight transposes ----
    const int t = bx - 2048;
    const int nbx = t % 80, k0 = (t / 80) * 32;
    const float* W;
    u16* Wt;
    int N, nb;
    if (nbx < 48)      { W = qkv_w;  Wt = fused_wt;                      N = 1536; nb = nbx; }
    else if (nbx < 64) { W = gate_w; Wt = fused_wt + (size_t)1536 * 512; N = 512;  nb = nbx - 48; }
    else               { W = out_w;  Wt = out_wt;                        N = 512;  nb = nbx - 64; }
    const int n0 = nb * 32;
    const int tx = tid & 31, ty = tid >> 5;
    #pragma unroll
    for (int yy = ty; yy < 32; yy += 8)
      tile[yy][tx] = W[(size_t)(k0 + yy) * N + n0 + tx];
    __syncthreads();
    #pragma unroll
    for (int yy = ty; yy < 32; yy += 8)
      Wt[(size_t)(n0 + yy) * DMODEL + k0 + tx] = f2bf(tile[tx][yy]);
  } else {                               // ---- bias table ----
    const int d = (bx - 3328) * 256 + tid;   // 0..2047
    if (d < NSEQ) {
      int bkt;
      if (d < 28) {
        bkt = d;
      } else {
        double tt = log((double)d / 28.0) / log(2048.0 / 28.0) * 16.0;
        int ti = 28 + (int)tt;
        bkt = ti < 43 ? ti : 43;
      }
      const int lo[8] = {38, 34, 28, 20, 13, 7, 3, 0};
      const int hi[8] = {44, 40, 35, 28, 21, 14, 9, 6};
      #pragma unroll
      for (int h = 0; h < HNUM; ++h) {
        bool inb = (bkt >= lo[h]) && (bkt < hi[h]);
        bias_tab[h * NSEQ + d] = inb ? pos_bias[bkt * HNUM + h] : -100.0f;
      }
    }
  }
}

// ---------------------------------------------------------------------------
// Prep: vbf[b,h,n,d] -> vbfT[b,h,d,n] (64x64 LDS tile transpose)
// ---------------------------------------------------------------------------
__global__ __launch_bounds__(256) void transpose_v_kernel(
    const u16* __restrict__ v, u16* __restrict__ vT) {
  __shared__ u16 t[64][LP];
  const int n0 = blockIdx.x * 64;
  const size_t bh = blockIdx.y;
  const int r = threadIdx.x >> 2, c0 = (threadIdx.x & 3) << 4;
  const u16* src = v + (bh * NSEQ + n0 + r) * HDIM + c0;
  u16x8 a0 = *(const u16x8*)src;
  u16x8 a1 = *(const u16x8*)(src + 8);
  #pragma unroll
  for (int j = 0; j < 8; ++j) {
    t[c0 + j][r] = a0[j];
    t[c0 + 8 + j][r] = a1[j];
  }
  __syncthreads();
  u16x8 o0 = *(const u16x8*)&t[r][c0];
  u16x8 o1 = *(const u16x8*)&t[r][c0 + 8];
  u16* dst = vT + (bh * HDIM + r) * NSEQ + n0 + c0;
  *(u16x8*)dst = o0;
  *(u16x8*)(dst + 8) = o1;
}

// ---------------------------------------------------------------------------
// Fused qkv+gate GEMM: 128x256 tile, BK=32, 512 threads, 2 blocks/CU,
// single-barrier 3-deep counted-vmcnt loop. NO lgkmcnt/sched pin between
// ds_read and MFMA — compiler schedules fine-grained lgkmcnt (m97 property).
// ---------------------------------------------------------------------------
__global__ __launch_bounds__(512, 4) void gemm_fused(
    const u16* __restrict__ Abf, const u16* __restrict__ Wt,
    const float* __restrict__ qkv_b, const float* __restrict__ gate_b,
    const float* __restrict__ kdelta, const float* __restrict__ vdelta,
    u16* __restrict__ qbf, u16* __restrict__ kbf, u16* __restrict__ vbf,
    u16* __restrict__ gate) {
  __shared__ __align__(16) u16 S[36864];   // 72 KB
  u16* SA3[3] = {S, S + 4096, S + 8192};
  u16* SB3[3] = {S + 12288, S + 20480, S + 28672};

  // XCD band map: XCD x owns m-tiles 8x..8x+7 (1MB A) x all n (2MB W)
  const int bid = blockIdx.x;
  const int xcd = bid & 7, loc = bid >> 3;
  const int m0 = (xcd * 8 + (loc & 7)) * 128;
  const int n0 = (loc >> 3) * 256;

  const int tid = threadIdx.x;
  const int w = tid >> 6, l = tid & 63, li = l & 15, lg = l >> 4;
  const int wm = w >> 2, wn = w & 3;

  f32x4 acc[4][4];
  #pragma unroll
  for (int i = 0; i < 4; ++i)
    #pragma unroll
    for (int j = 0; j < 4; ++j) acc[i][j] = f32x4{0.f, 0.f, 0.f, 0.f};

  const u16* Ab = Abf + (size_t)m0 * DMODEL;
  const u16* Bb = Wt + (size_t)n0 * DMODEL;

  stageAB(SA3[0], SB3[0], Ab, Bb, tid);
  stageAB(SA3[1], SB3[1], Ab + 32, Bb + 32, tid);

  #pragma unroll
  for (int kt = 0; kt < 16; ++kt) {
    if (kt <= 14) asm volatile("s_waitcnt vmcnt(3)" ::: "memory");
    else          asm volatile("s_waitcnt vmcnt(0)" ::: "memory");
    __builtin_amdgcn_s_barrier();        // all waves done reading tile kt-1
    __builtin_amdgcn_sched_barrier(0);   // pin stage/reads after barrier
    const u16* Asb = SA3[kt % 3];
    const u16* Bsb = SB3[kt % 3];
    u16x8 af[4], bfr[4];
    #pragma unroll
    for (int mt = 0; mt < 4; ++mt)
      af[mt] = *(const u16x8*)&Asb[swz_off(wm * 64 + mt * 16 + li, lg)];
    #pragma unroll
    for (int nt = 0; nt < 4; ++nt)
      bfr[nt] = *(const u16x8*)&Bsb[swz_off(wn * 64 + nt * 16 + li, lg)];
    if (kt + 2 < 16)                     // safe: buffer (kt+2)%3 = (kt-1)%3
      stageAB(SA3[(kt + 2) % 3], SB3[(kt + 2) % 3],
              Ab + (kt + 2) * 32, Bb + (kt + 2) * 32, tid);
    // compiler inserts fine-grained lgkmcnt for af/bfr dependencies
    #pragma unroll
    for (int mt = 0; mt < 4; ++mt)
      #pragma unroll
      for (int nt = 0; nt < 4; ++nt)
        acc[mt][nt] = mfma_bf16(af[mt], bfr[nt], acc[mt][nt]);
  }
  __syncthreads();                       // all reads done before S reuse

  // ---- epilogue: acc+bias -> padded LDS C-tile (128x256, stride CPE) ----
  u16* Ct = S;
  const int seg = n0 >> 9;                   // 0=q 1=k 2=v 3=gate (uniform)
  const int nin = n0 & 511;                  // 0 or 256
  #pragma unroll
  for (int nt = 0; nt < 4; ++nt) {
    const int col = wn * 64 + nt * 16 + li;
    const int colg = n0 + col;
    const float bv = (seg < 3) ? qkv_b[colg] : gate_b[colg & 511];
    #pragma unroll
    for (int mt = 0; mt < 4; ++mt) {
      const int row = wm * 64 + mt * 16 + lg * 4;
      #pragma unroll
      for (int r = 0; r < 4; ++r)
        Ct[(row + r) * CPE + col] = f2bf(acc[mt][nt][r] + bv);
    }
  }
  __syncthreads();

  // ---- packed coalesced writes from LDS (8 u16x8 per thread) ----
  #pragma unroll
  for (int p = 0; p < 8; ++p) {
    const int idx = p * 512 + tid;
    const int row = idx >> 5, ccol = (idx & 31) * 8;
    const int rg = m0 + row;
    const int bb = rg >> 11, n = rg & 2047;
    u16x8 cv = *(const u16x8*)&Ct[row * CPE + ccol];
    const int cws = nin + ccol;              // col within 512-wide segment
    if (seg == 3) {
      u16x8 o;
      #pragma unroll
      for (int j = 0; j < 8; ++j)
        o[j] = f2bf(1.f / (1.f + __expf(-bf2f(cv[j]))));
      *(u16x8*)&gate[(size_t)rg * DMODEL + cws] = o;
    } else {
      const int hh = cws >> 6, hd = cws & 63;
      const size_t hidx = (((size_t)bb * HNUM + hh) * NSEQ + n) * HDIM + hd;
      if (seg == 0) {
        u16x8 o;
        #pragma unroll
        for (int j = 0; j < 8; ++j) o[j] = f2bf(bf2f(cv[j]) * 0.125f);
        *(u16x8*)&qbf[hidx] = o;
      } else {
        const float* dp = (seg == 1 ? kdelta : vdelta) + hidx;
        float4 d0 = *(const float4*)dp;
        float4 d1 = *(const float4*)(dp + 4);
        u16x8 o;
        o[0] = f2bf(bf2f(cv[0]) + d0.x); o[1] = f2bf(bf2f(cv[1]) + d0.y);
        o[2] = f2bf(bf2f(cv[2]) + d0.z); o[3] = f2bf(bf2f(cv[3]) + d0.w);
        o[4] = f2bf(bf2f(cv[4]) + d1.x); o[5] = f2bf(bf2f(cv[5]) + d1.y);
        o[6] = f2bf(bf2f(cv[6]) + d1.z); o[7] = f2bf(bf2f(cv[7]) + d1.w);
        *(u16x8*)&((seg == 1) ? kbf : vbf)[hidx] = o;
      }
    }
  }
}

// ---------------------------------------------------------------------------
// Out GEMM: 64x128 tile, BK=32, single-barrier 3-deep loop, unpinned sched.
// ---------------------------------------------------------------------------
__global__ __launch_bounds__(256) void gemm_out(
    const u16* __restrict__ Abf, const u16* __restrict__ Wt,
    const float* __restrict__ bias, float* __restrict__ outf) {
  __shared__ __align__(16) u16 As[3][64 * 32];
  __shared__ __align__(16) u16 Bs[3][128 * 32];

  const int m0 = blockIdx.y * 64, n0 = blockIdx.x * 128;
  const int tid = threadIdx.x;
  const int w = tid >> 6, l = tid & 63, li = l & 15, lg = l >> 4;
  const int wr = w >> 1, wc = w & 1;

  f32x4 acc[2][4];
  #pragma unroll
  for (int i = 0; i < 2; ++i)
    #pragma unroll
    for (int j = 0; j < 4; ++j) acc[i][j] = f32x4{0.f, 0.f, 0.f, 0.f};

  const u16* Ab = Abf + (size_t)m0 * DMODEL;
  const u16* Bb = Wt + (size_t)n0 * DMODEL;

  stage_tile<64>(As[0], Ab, tid);
  stage_tile<128>(Bs[0], Bb, tid);
  stage_tile<64>(As[1], Ab + 32, tid);
  stage_tile<128>(Bs[1], Bb + 32, tid);

  #pragma unroll
  for (int kt = 0; kt < 16; ++kt) {
    if (kt <= 14) asm volatile("s_waitcnt vmcnt(3)" ::: "memory");
    else          asm volatile("s_waitcnt vmcnt(0)" ::: "memory");
    __builtin_amdgcn_s_barrier();
    __builtin_amdgcn_sched_barrier(0);
    const u16* Asb = As[kt % 3];
    const u16* Bsb = Bs[kt % 3];
    u16x8 af[2], bfr[4];
    #pragma unroll
    for (int mt = 0; mt < 2; ++mt)
      af[mt] = *(const u16x8*)&Asb[swz_off(wr * 32 + mt * 16 + li, lg)];
    #pragma unroll
    for (int nt = 0; nt < 4; ++nt)
      bfr[nt] = *(const u16x8*)&Bsb[swz_off(wc * 64 + nt * 16 + li, lg)];
    if (kt + 2 < 16) {
      stage_tile<64>(As[(kt + 2) % 3], Ab + (kt + 2) * 32, tid);
      stage_tile<128>(Bs[(kt + 2) % 3], Bb + (kt + 2) * 32, tid);
    }
    #pragma unroll
    for (int mt = 0; mt < 2; ++mt)
      #pragma unroll
      for (int nt = 0; nt < 4; ++nt)
        acc[mt][nt] = mfma_bf16(af[mt], bfr[nt], acc[mt][nt]);
  }

  #pragma unroll
  for (int nt = 0; nt < 4; ++nt) {
    const int colg = n0 + wc * 64 + nt * 16 + li;
    const float bv = bias[colg];
    #pragma unroll
    for (int mt = 0; mt < 2; ++mt) {
      #pragma unroll
      for (int r = 0; r < 4; ++r) {
        const int rowg = m0 + wr * 32 + mt * 16 + lg * 4 + r;
        outf[(size_t)rowg * DMODEL + colg] = acc[mt][nt][r] + bv;
      }
    }
  }
}

// ---------------------------------------------------------------------------
// Flash attention (round-16 verified: staged body + T14 async-STAGE split).
// Slots: h0 x8 (0-7), h1 x4 (8-11), h2 x2 (12-13), h3..h7 direct (14-18).
// ---------------------------------------------------------------------------
__global__ __launch_bounds__(256) void attn_kernel(
    const u16* __restrict__ qbf, const u16* __restrict__ kbf,
    const u16* __restrict__ vbfT, const float* __restrict__ bias_tab,
    const float* __restrict__ if_gain, const u16* __restrict__ gate,
    u16* __restrict__ attn_out, u16* __restrict__ partO,
    float* __restrict__ partM, float* __restrict__ partL) {
  __shared__ __align__(16) u16 Ks[64][LP];   // [kv][hd]
  __shared__ __align__(16) u16 Vt[64][LP];   // [hd][kv]
  __shared__ __align__(16) u16 Pl[4][16][LP];

  static const int DMINW[8] = {408, 139, 26, 18, 11, 5, 1, 0};
  static const int DMAXW[8] = {2049, 702, 185, 29, 22, 15, 10, 7};
  static const int DMINS[8] = {412, 143, 30, 22, 15, 9, 5, 2};
  static const int SH[19] = {0,0,0,0,0,0,0,0, 1,1,1,1, 2,2, 3,4,5,6,7};
  static const int SC[19] = {0,1,2,3,4,5,6,7, 0,1,2,3, 0,1, 0,0,0,0,0};
  static const int SN[19] = {8,8,8,8,8,8,8,8, 4,4,4,4, 2,2, 1,1,1,1,1};

  const int slot = blockIdx.x >> 7;
  const int rem = blockIdx.x & 127;
  const int qt = 31 - (rem >> 2);
  const int b = rem & 3;
  const int h = SH[slot], ch = SC[slot], nc = SN[slot];
  const int bh = b * HNUM + h;
  const int q0 = qt * 64;
  const int tid = threadIdx.x;
  const int w = tid >> 6, l = tid & 63, li = l & 15, lg = l >> 4;

  const u16* qrow = qbf + ((size_t)bh * NSEQ + q0 + w * 16 + li) * HDIM;
  u16x8 qf0 = *(const u16x8*)(qrow + lg * 8);
  u16x8 qf1 = *(const u16x8*)(qrow + 32 + lg * 8);

  const bool pure = q0 >= DMINS[h];
  int kv_lo = 0, kv_hi = q0 + 64;
  if (pure) {
    int lo = q0 - DMAXW[h];
    kv_lo = (lo > 0 ? lo : 0) & ~63;
    kv_hi = q0 + 64 - DMINW[h];
  }
  const int t0 = kv_lo >> 6, t1 = (kv_hi - 1) >> 6;
  const int len = t1 - t0 + 1;
  const int ta = t0 + (len * ch) / nc;
  const int tb = t0 + (len * (ch + 1)) / nc - 1;

  const int srow = tid >> 2;
  const int scb = (tid & 3) << 4;
  const float* btab = bias_tab + h * NSEQ;

  // T14 prologue: load tile ta into registers
  u16x8 kr0, kr1, vr0, vr1;
  {
    const int kv0 = ta << 6;
    const size_t kbase = ((size_t)bh * NSEQ + kv0 + srow) * HDIM + scb;
    kr0 = *(const u16x8*)(kbf + kbase);
    kr1 = *(const u16x8*)(kbf + kbase + 8);
    const size_t vbase = ((size_t)bh * HDIM + srow) * NSEQ + kv0 + scb;
    vr0 = *(const u16x8*)(vbfT + vbase);
    vr1 = *(const u16x8*)(vbfT + vbase + 8);
  }

  float mrun = -INFINITY, lrun = 0.f;
  f32x4 O[4] = {{0.f,0.f,0.f,0.f},{0.f,0.f,0.f,0.f},
                {0.f,0.f,0.f,0.f},{0.f,0.f,0.f,0.f}};

  for (int tt = ta; tt <= tb; ++tt) {
    const int kv0 = tt << 6;
    // ---- write staged regs -> LDS ----
    *(u16x8*)&Ks[srow][scb] = kr0;
    *(u16x8*)&Ks[srow][scb + 8] = kr1;
    *(u16x8*)&Vt[srow][scb] = vr0;
    *(u16x8*)&Vt[srow][scb + 8] = vr1;
    __syncthreads();

    // ---- T14: issue NEXT tile's global loads (consumed next iteration) ----
    if (tt < tb) {
      const int kv1 = (tt + 1) << 6;
      const size_t kbase = ((size_t)bh * NSEQ + kv1 + srow) * HDIM + scb;
      kr0 = *(const u16x8*)(kbf + kbase);
      kr1 = *(const u16x8*)(kbf + kbase + 8);
      const size_t vbase = ((size_t)bh * HDIM + srow) * NSEQ + kv1 + scb;
      vr0 = *(const u16x8*)(vbfT + vbase);
      vr1 = *(const u16x8*)(vbfT + vbase + 8);
    }

    // ---- S^T = K Q^T : 4 j-tiles x (K=64 -> 2 mfma) ----
    f32x4 s[4];
    #pragma unroll
    for (int t = 0; t < 4; ++t) {
      u16x8 a0 = *(const u16x8*)&Ks[t * 16 + li][lg * 8];
      u16x8 a1 = *(const u16x8*)&Ks[t * 16 + li][32 + lg * 8];
      f32x4 acc = {0.f, 0.f, 0.f, 0.f};
      acc = mfma_bf16(a0, qf0, acc);
      acc = mfma_bf16(a1, qf1, acc);
      s[t] = acc;
    }

    const int D0 = (q0 + w * 16 + li) - kv0 - lg * 4;
    float rm = -1e30f;
    #pragma unroll
    for (int t = 0; t < 4; ++t) {
      #pragma unroll
      for (int r = 0; r < 4; ++r) {
        int d = D0 - 16 * t - r;
        float sv = s[t][r];
        sv = (d >= 0) ? (sv + btab[d]) : -1e30f;
        s[t][r] = sv;
        rm = fmaxf(rm, sv);
      }
    }
    rm = fmaxf(rm, __shfl_xor(rm, 16, 64));
    rm = fmaxf(rm, __shfl_xor(rm, 32, 64));
    const float mn = fmaxf(mrun, rm);
    const float f = __expf(mrun - mn);
    mrun = mn;
    float ps = 0.f;
    #pragma unroll
    for (int t = 0; t < 4; ++t) {
      #pragma unroll
      for (int r = 0; r < 4; ++r) {
        float p = __expf(s[t][r] - mn);
        s[t][r] = p;
        ps += p;
      }
    }
    ps += __shfl_xor(ps, 16, 64);
    ps += __shfl_xor(ps, 32, 64);
    lrun = lrun * f + ps;

    #pragma unroll
    for (int t = 0; t < 4; ++t) {
      u16x4 pk;
      pk[0] = f2bf(s[t][0]); pk[1] = f2bf(s[t][1]);
      pk[2] = f2bf(s[t][2]); pk[3] = f2bf(s[t][3]);
      *(u16x4*)&Pl[w][li][t * 16 + lg * 4] = pk;
    }

    float fr[4];
    #pragma unroll
    for (int r = 0; r < 4; ++r) fr[r] = __shfl(f, lg * 4 + r, 64);
    #pragma unroll
    for (int dt = 0; dt < 4; ++dt) {
      O[dt][0] *= fr[0]; O[dt][1] *= fr[1];
      O[dt][2] *= fr[2]; O[dt][3] *= fr[3];
    }
    __syncthreads();

    #pragma unroll
    for (int ks = 0; ks < 2; ++ks) {
      u16x8 pA = *(const u16x8*)&Pl[w][li][ks * 32 + lg * 8];
      #pragma unroll
      for (int dt = 0; dt < 4; ++dt) {
        u16x8 vB = *(const u16x8*)&Vt[dt * 16 + li][ks * 32 + lg * 8];
        O[dt] = mfma_bf16(pA, vB, O[dt]);
      }
    }
    __syncthreads();
  }

  if (nc == 1) {
    const float gain = if_gain[h];
    float linv[4];
    #pragma unroll
    for (int r = 0; r < 4; ++r)
      linv[r] = gain / __shfl(lrun, lg * 4 + r, 64);
    #pragma unroll
    for (int r = 0; r < 4; ++r) {
      const int i = q0 + w * 16 + lg * 4 + r;
      const size_t base = ((size_t)b * NSEQ + i) * DMODEL + h * HDIM + li;
      #pragma unroll
      for (int dt = 0; dt < 4; ++dt) {
        const float g = bf2f(gate[base + dt * 16]);
        attn_out[base + dt * 16] = f2bf(O[dt][r] * linv[r] * g);
      }
    }
  } else {
    const int sbase = (b * 32 + qt) * NSLOT + slot;   // slot in 0..13 here
    #pragma unroll
    for (int r = 0; r < 4; ++r) {
      const int rl = w * 16 + lg * 4 + r;
      #pragma unroll
      for (int dt = 0; dt < 4; ++dt)
        partO[(size_t)sbase * 4096 + rl * 64 + dt * 16 + li] = f2bf(O[dt][r]);
    }
    if (lg == 0) {
      partM[sbase * 64 + w * 16 + li] = mrun;
      partL[sbase * 64 + w * 16 + li] = lrun;
    }
  }
}

// ---------------------------------------------------------------------------
// Combine split-KV partials: h0 (8 chunks), h1 (4), h2 (2).
// ---------------------------------------------------------------------------
__global__ __launch_bounds__(256) void combine_kernel(
    const u16* __restrict__ partO, const float* __restrict__ partM,
    const float* __restrict__ partL, const float* __restrict__ if_gain,
    const u16* __restrict__ gate, u16* __restrict__ attn_out) {
  const int b = blockIdx.x & 3, qt = blockIdx.x >> 2;
  const int tid = threadIdx.x;
  const int row = tid >> 2, d0 = (tid & 3) << 4;
  static const int HNC[3] = {8, 4, 2};
  static const int HS0[3] = {0, 8, 12};

  #pragma unroll
  for (int hc = 0; hc < 3; ++hc) {
    const int nc = HNC[hc], s0 = HS0[hc];
    const int sbase = (b * 32 + qt) * NSLOT + s0;
    float m[8];
    float M = -INFINITY;
    #pragma unroll
    for (int c = 0; c < 8; ++c) {
      m[c] = (c < nc) ? partM[(sbase + c) * 64 + row] : -INFINITY;
      M = fmaxf(M, m[c]);
    }
    float wch[8];
    float den = 0.f;
    #pragma unroll
    for (int c = 0; c < 8; ++c) {
      wch[c] = (c < nc) ? __expf(m[c] - M) : 0.f;
      if (c < nc) den += wch[c] * partL[(sbase + c) * 64 + row];
    }
    float num[16];
    #pragma unroll
    for (int j = 0; j < 16; ++j) num[j] = 0.f;
    #pragma unroll
    for (int c = 0; c < 8; ++c) {
      if (c < nc) {
        const u16* op = partO + (size_t)(sbase + c) * 4096 + row * 64 + d0;
        u16x8 o0 = *(const u16x8*)op;
        u16x8 o1 = *(const u16x8*)(op + 8);
        #pragma unroll
        for (int j = 0; j < 8; ++j) {
          num[j]     += wch[c] * bf2f(o0[j]);
          num[8 + j] += wch[c] * bf2f(o1[j]);
        }
      }
    }
    const float inv = if_gain[hc] / den;
    const size_t obase =
        ((size_t)b * NSEQ + qt * 64 + row) * DMODEL + hc * HDIM + d0;
    u16x8 g0 = *(const u16x8*)(gate + obase);
    u16x8 g1 = *(const u16x8*)(gate + obase + 8);
    u16x8 r0, r1;
    #pragma unroll
    for (int j = 0; j < 8; ++j) {
      r0[j] = f2bf(num[j] * inv * bf2f(g0[j]));
      r1[j] = f2bf(num[8 + j] * inv * bf2f(g1[j]));
    }
    *(u16x8*)(attn_out + obase) = r0;
    *(u16x8*)(attn_out + obase + 8) = r1;
  }
}

// ---------------------------------------------------------------------------
extern "C" void kernel_launch(void* const* d_in, const int* in_sizes, int n_in,
                              void* d_out, int out_size, void* d_ws,
                              size_t ws_size, hipStream_t stream) {
  const float* x       = (const float*)d_in[0];
  const float* k_delta = (const float*)d_in[1];
  const float* v_delta = (const float*)d_in[2];
  const float* qkv_w   = (const float*)d_in[3];
  const float* qkv_b   = (const float*)d_in[4];
  const float* gate_w  = (const float*)d_in[5];
  const float* gate_b  = (const float*)d_in[6];
  const float* out_w   = (const float*)d_in[7];
  const float* out_b   = (const float*)d_in[8];
  const float* pos_bias = (const float*)d_in[9];
  const float* if_gain  = (const float*)d_in[10];
  float* out = (float*)d_out;
  char* ws = (char*)d_ws;

  // workspace layout (bytes)
  u16*   xbf      = (u16*)(ws + 0);              //  8,388,608 (dead after gemm)
  u16*   qbf      = (u16*)(ws + 8388608);        //  8,388,608
  u16*   kbf      = (u16*)(ws + 16777216);       //  8,388,608
  u16*   vbf      = (u16*)(ws + 25165824);       //  8,388,608 (dead after v-T)
  u16*   vbfT     = (u16*)(ws + 33554432);       //  8,388,608
  u16*   gate_buf = (u16*)(ws + 41943040);       //  8,388,608
  u16*   fused_wt = (u16*)(ws + 50331648);       //  2,097,152
  u16*   out_wt   = (u16*)(ws + 52428800);       //    524,288
  float* bias_tab = (float*)(ws + 52953088);     //     65,536
  u16*   partO = (u16*)(ws + 53018624);          // 14,680,064
  float* partM = (float*)(ws + 67698688);        //    458,752
  float* partL = (float*)(ws + 68157440);        //    458,752
  u16*   attn_buf = vbf;                         // vbf dead after transpose_v

  // merged prep (cvt + weight transposes + bias table)
  prep_kernel<<<dim3(3336), dim3(256), 0, stream>>>(
      x, qkv_w, gate_w, out_w, pos_bias, xbf, fused_wt, out_wt, bias_tab);

  // fused qkv+gate GEMM, 128x256 tile, 512 threads, 2 blocks/CU
  gemm_fused<<<dim3(512), dim3(512), 0, stream>>>(
      xbf, fused_wt, qkv_b, gate_b, k_delta, v_delta,
      qbf, kbf, vbf, gate_buf);

  // v -> v^T
  transpose_v_kernel<<<dim3(32, 32), dim3(256), 0, stream>>>(vbf, vbfT);

  // flash attention: split-KV balanced chunks (19 slots), T14 staged
  attn_kernel<<<dim3(2432), dim3(256), 0, stream>>>(
      qbf, kbf, vbfT, bias_tab, if_gain, gate_buf, attn_buf,
      partO, partM, partL);

  // merge h0/h1/h2 partials
  combine_kernel<<<dim3(128), dim3(256), 0, stream>>>(
      partO, partM, partL, if_gain, gate_buf, attn_buf);

  // final GEMM -> d_out (fp32)
  gemm_out<<<dim3(4, 128), dim3(256), 0, stream>>>(
      attn_buf, out_wt, out_b, out);

  (void)in_sizes; (void)n_in; (void)out_size; (void)ws_size;
}

// Round 18
// 83.367 us; speedup vs baseline: 1.4351x; 1.0438x over previous
//
#include <hip/hip_runtime.h>
#include <cmath>

typedef unsigned short u16;
typedef unsigned short u16x4 __attribute__((ext_vector_type(4)));
typedef unsigned short u16x8 __attribute__((ext_vector_type(8)));
typedef __bf16 bf16x8 __attribute__((ext_vector_type(8)));
typedef float f32x4 __attribute__((ext_vector_type(4)));

#define HNUM 8
#define HDIM 64
#define BATCH 4
#define NSEQ 2048
#define DMODEL 512
#define LP 72    // padded LDS row stride (u16) for attn
#define CPE 264  // padded C-tile row stride (u16) in gemm_fused epilogue
#define CPT 136  // padded TRANSPOSED C-tile row stride (u16) for V blocks
#define NSLOT 14 // split partial slots per (b,qt): h0 x8 + h1 x4 + h2 x2

__device__ __forceinline__ u16 f2bf(float f) {
  unsigned int u = __builtin_bit_cast(unsigned int, f);
  u += 0x7fffu + ((u >> 16) & 1u);          // round-to-nearest-even
  return (u16)(u >> 16);
}

__device__ __forceinline__ float bf2f(u16 v) {
  unsigned int u = ((unsigned int)v) << 16;
  return __builtin_bit_cast(float, u);
}

__device__ __forceinline__ f32x4 mfma_bf16(u16x8 a, u16x8 b, f32x4 c) {
  return __builtin_amdgcn_mfma_f32_16x16x32_bf16(
      __builtin_bit_cast(bf16x8, a), __builtin_bit_cast(bf16x8, b), c, 0, 0, 0);
}

// async global->LDS, 16 B per lane (dest must be wave-uniform base + lane*16)
__device__ __forceinline__ void gload16(u16* lds, const u16* g) {
  __builtin_amdgcn_global_load_lds(
      (const __attribute__((address_space(1))) void*)g,
      (__attribute__((address_space(3))) void*)lds, 16, 0, 0);
}

// chunk-XOR swizzle (rounds 10-17 verified): linear LDS dest, inverse-swizzled
// global source; read with the same XOR. 32-col (BK=32) tiles.
__device__ __forceinline__ int swz_off(int row, int lg) {
  return row * 32 + ((lg ^ ((row >> 1) & 3)) << 3);
}

// 256-thread staging (gemm_out)
template <int ROWS>
__device__ __forceinline__ void stage_tile(u16* lds, const u16* g, int tid) {
  #pragma unroll
  for (int i = 0; i < ROWS / 64; ++i) {
    const int t = i * 256 + tid;
    const int row = t >> 2;
    const int ch = (t & 3) ^ ((row >> 1) & 3);
    gload16(lds + t * 8, g + (size_t)row * DMODEL + ch * 8);
  }
}

// 512-thread staging of A(128x32) + B(256x32), 3 loads/thread
__device__ __forceinline__ void stageAB(u16* ldsA, u16* ldsB, const u16* gA,
                                        const u16* gB, int tid) {
  {
    const int s = tid;                       // A: 512 loads
    const int row = s >> 2;
    const int ch = (s & 3) ^ ((row >> 1) & 3);
    gload16(ldsA + s * 8, gA + (size_t)row * DMODEL + ch * 8);
  }
  #pragma unroll
  for (int i = 0; i < 2; ++i) {              // B: 1024 loads
    const int s = i * 512 + tid;
    const int row = s >> 2;
    const int ch = (s & 3) ^ ((row >> 1) & 3);
    gload16(ldsB + s * 8, gB + (size_t)row * DMODEL + ch * 8);
  }
}

// ---------------------------------------------------------------------------
// Merged prep kernel: blockIdx.x decodes role.
//   [0, 2048)        : x fp32 -> bf16 (8 elems/thread)
//   [2048, 3328)     : weight transposes (80 n-blocks x 16 k-blocks)
//   [3328, 3336)     : bias table
// ---------------------------------------------------------------------------
__global__ __launch_bounds__(256) void prep_kernel(
    const float* __restrict__ x, const float* __restrict__ qkv_w,
    const float* __restrict__ gate_w, const float* __restrict__ out_w,
    const float* __restrict__ pos_bias, u16* __restrict__ xbf,
    u16* __restrict__ fused_wt, u16* __restrict__ out_wt,
    float* __restrict__ bias_tab) {
  __shared__ float tile[32][33];
  const int bx = blockIdx.x;
  const int tid = threadIdx.x;

  if (bx < 2048) {                       // ---- cvt x -> bf16 ----
    const int i = bx * 256 + tid;        // n8 = 524288 exactly
    const float4 f0 = *(const float4*)(x + (size_t)i * 8);
    const float4 f1 = *(const float4*)(x + (size_t)i * 8 + 4);
    u16x8 pk;
    pk[0] = f2bf(f0.x); pk[1] = f2bf(f0.y); pk[2] = f2bf(f0.z); pk[3] = f2bf(f0.w);
    pk[4] = f2bf(f1.x); pk[5] = f2bf(f1.y); pk[6] = f2bf(f1.z); pk[7] = f2bf(f1.w);
    *(u16x8*)(xbf + (size_t)i * 8) = pk;
  } else if (bx < 3328) {                // ---- weight transposes ----
    const int t = bx - 2048;
    const int nbx = t % 80, k0 = (t / 80) * 32;
    const float* W;
    u16* Wt;
    int N, nb;
    if (nbx < 48)      { W = qkv_w;  Wt = fused_wt;                      N = 1536; nb = nbx; }
    else if (nbx < 64) { W = gate_w; Wt = fused_wt + (size_t)1536 * 512; N = 512;  nb = nbx - 48; }
    else               { W = out_w;  Wt = out_wt;                        N = 512;  nb = nbx - 64; }
    const int n0 = nb * 32;
    const int tx = tid & 31, ty = tid >> 5;
    #pragma unroll
    for (int yy = ty; yy < 32; yy += 8)
      tile[yy][tx] = W[(size_t)(k0 + yy) * N + n0 + tx];
    __syncthreads();
    #pragma unroll
    for (int yy = ty; yy < 32; yy += 8)
      Wt[(size_t)(n0 + yy) * DMODEL + k0 + tx] = f2bf(tile[tx][yy]);
  } else {                               // ---- bias table ----
    const int d = (bx - 3328) * 256 + tid;   // 0..2047
    if (d < NSEQ) {
      int bkt;
      if (d < 28) {
        bkt = d;
      } else {
        double tt = log((double)d / 28.0) / log(2048.0 / 28.0) * 16.0;
        int ti = 28 + (int)tt;
        bkt = ti < 43 ? ti : 43;
      }
      const int lo[8] = {38, 34, 28, 20, 13, 7, 3, 0};
      const int hi[8] = {44, 40, 35, 28, 21, 14, 9, 6};
      #pragma unroll
      for (int h = 0; h < HNUM; ++h) {
        bool inb = (bkt >= lo[h]) && (bkt < hi[h]);
        bias_tab[h * NSEQ + d] = inb ? pos_bias[bkt * HNUM + h] : -100.0f;
      }
    }
  }
}

// ---------------------------------------------------------------------------
// Fused qkv+gate GEMM: 128x256 tile, BK=32, 512 threads, 2 blocks/CU,
// single-barrier 3-deep counted-vmcnt loop, unpinned MFMA scheduling
// (round-17 verified). Epilogue: q/k/gate via row-major C-tile; V blocks
// write the TRANSPOSED C-tile and emit vbfT[b,h,d,n] directly (coalesced
// 256B runs along n) — transpose_v kernel eliminated.
// ---------------------------------------------------------------------------
__global__ __launch_bounds__(512, 4) void gemm_fused(
    const u16* __restrict__ Abf, const u16* __restrict__ Wt,
    const float* __restrict__ qkv_b, const float* __restrict__ gate_b,
    const float* __restrict__ kdelta, const float* __restrict__ vdelta,
    u16* __restrict__ qbf, u16* __restrict__ kbf, u16* __restrict__ vbfT,
    u16* __restrict__ gate) {
  __shared__ __align__(16) u16 S[36864];   // 72 KB
  u16* SA3[3] = {S, S + 4096, S + 8192};
  u16* SB3[3] = {S + 12288, S + 20480, S + 28672};

  // XCD band map: XCD x owns m-tiles 8x..8x+7 (1MB A) x all n (2MB W)
  const int bid = blockIdx.x;
  const int xcd = bid & 7, loc = bid >> 3;
  const int m0 = (xcd * 8 + (loc & 7)) * 128;
  const int n0 = (loc >> 3) * 256;

  const int tid = threadIdx.x;
  const int w = tid >> 6, l = tid & 63, li = l & 15, lg = l >> 4;
  const int wm = w >> 2, wn = w & 3;

  f32x4 acc[4][4];
  #pragma unroll
  for (int i = 0; i < 4; ++i)
    #pragma unroll
    for (int j = 0; j < 4; ++j) acc[i][j] = f32x4{0.f, 0.f, 0.f, 0.f};

  const u16* Ab = Abf + (size_t)m0 * DMODEL;
  const u16* Bb = Wt + (size_t)n0 * DMODEL;

  stageAB(SA3[0], SB3[0], Ab, Bb, tid);
  stageAB(SA3[1], SB3[1], Ab + 32, Bb + 32, tid);

  #pragma unroll
  for (int kt = 0; kt < 16; ++kt) {
    if (kt <= 14) asm volatile("s_waitcnt vmcnt(3)" ::: "memory");
    else          asm volatile("s_waitcnt vmcnt(0)" ::: "memory");
    __builtin_amdgcn_s_barrier();        // all waves done reading tile kt-1
    __builtin_amdgcn_sched_barrier(0);   // pin stage/reads after barrier
    const u16* Asb = SA3[kt % 3];
    const u16* Bsb = SB3[kt % 3];
    u16x8 af[4], bfr[4];
    #pragma unroll
    for (int mt = 0; mt < 4; ++mt)
      af[mt] = *(const u16x8*)&Asb[swz_off(wm * 64 + mt * 16 + li, lg)];
    #pragma unroll
    for (int nt = 0; nt < 4; ++nt)
      bfr[nt] = *(const u16x8*)&Bsb[swz_off(wn * 64 + nt * 16 + li, lg)];
    if (kt + 2 < 16)                     // safe: buffer (kt+2)%3 = (kt-1)%3
      stageAB(SA3[(kt + 2) % 3], SB3[(kt + 2) % 3],
              Ab + (kt + 2) * 32, Bb + (kt + 2) * 32, tid);
    // compiler inserts fine-grained lgkmcnt for af/bfr dependencies
    #pragma unroll
    for (int mt = 0; mt < 4; ++mt)
      #pragma unroll
      for (int nt = 0; nt < 4; ++nt)
        acc[mt][nt] = mfma_bf16(af[mt], bfr[nt], acc[mt][nt]);
  }
  __syncthreads();                       // all reads done before S reuse

  const int seg = n0 >> 9;                   // 0=q 1=k 2=v 3=gate (uniform)
  const int nin = n0 & 511;                  // 0 or 256

  if (seg == 2) {
    // ---- V path: TRANSPOSED C-tile (CtT[col][row]) + vdelta in phase 1 ----
    u16* CtT = S;                            // 256 x CPT u16 = 69.6 KB
    const int bb = m0 >> 11, m0n = m0 & 2047;
    #pragma unroll
    for (int nt = 0; nt < 4; ++nt) {
      const int col = wn * 64 + nt * 16 + li;
      const int cws = nin + col;
      const int hh = cws >> 6, hd = cws & 63;
      const float bv = qkv_b[2 * DMODEL + cws];
      const size_t dbase = (((size_t)bb * HNUM + hh) * NSEQ + m0n) * HDIM + hd;
      #pragma unroll
      for (int mt = 0; mt < 4; ++mt) {
        const int row = wm * 64 + mt * 16 + lg * 4;
        #pragma unroll
        for (int r = 0; r < 4; ++r)
          CtT[col * CPT + row + r] =
              f2bf(acc[mt][nt][r] + bv + vdelta[dbase + (size_t)(row + r) * HDIM]);
      }
    }
    __syncthreads();
    // ---- phase 2: LDS -> vbfT, 16-lane groups write 256B runs along n ----
    #pragma unroll
    for (int p = 0; p < 8; ++p) {
      const int a = p * 512 + tid;
      const int col = a >> 4, nc = a & 15;
      const int cws = nin + col;
      const int hh = cws >> 6, hd = cws & 63;
      u16x8 v = *(const u16x8*)&CtT[col * CPT + nc * 8];
      *(u16x8*)&vbfT[(((size_t)bb * HNUM + hh) * HDIM + hd) * NSEQ + m0n +
                     nc * 8] = v;
    }
  } else {
    // ---- q/k/gate path: row-major C-tile (round-17 verified) ----
    u16* Ct = S;
    #pragma unroll
    for (int nt = 0; nt < 4; ++nt) {
      const int col = wn * 64 + nt * 16 + li;
      const int colg = n0 + col;
      const float bv = (seg < 3) ? qkv_b[colg] : gate_b[colg & 511];
      #pragma unroll
      for (int mt = 0; mt < 4; ++mt) {
        const int row = wm * 64 + mt * 16 + lg * 4;
        #pragma unroll
        for (int r = 0; r < 4; ++r)
          Ct[(row + r) * CPE + col] = f2bf(acc[mt][nt][r] + bv);
      }
    }
    __syncthreads();
    #pragma unroll
    for (int p = 0; p < 8; ++p) {
      const int idx = p * 512 + tid;
      const int row = idx >> 5, ccol = (idx & 31) * 8;
      const int rg = m0 + row;
      const int bb = rg >> 11, n = rg & 2047;
      u16x8 cv = *(const u16x8*)&Ct[row * CPE + ccol];
      const int cws = nin + ccol;
      if (seg == 3) {
        u16x8 o;
        #pragma unroll
        for (int j = 0; j < 8; ++j)
          o[j] = f2bf(1.f / (1.f + __expf(-bf2f(cv[j]))));
        *(u16x8*)&gate[(size_t)rg * DMODEL + cws] = o;
      } else {
        const int hh = cws >> 6, hd = cws & 63;
        const size_t hidx = (((size_t)bb * HNUM + hh) * NSEQ + n) * HDIM + hd;
        if (seg == 0) {
          u16x8 o;
          #pragma unroll
          for (int j = 0; j < 8; ++j) o[j] = f2bf(bf2f(cv[j]) * 0.125f);
          *(u16x8*)&qbf[hidx] = o;
        } else {
          const float* dp = kdelta + hidx;
          float4 d0 = *(const float4*)dp;
          float4 d1 = *(const float4*)(dp + 4);
          u16x8 o;
          o[0] = f2bf(bf2f(cv[0]) + d0.x); o[1] = f2bf(bf2f(cv[1]) + d0.y);
          o[2] = f2bf(bf2f(cv[2]) + d0.z); o[3] = f2bf(bf2f(cv[3]) + d0.w);
          o[4] = f2bf(bf2f(cv[4]) + d1.x); o[5] = f2bf(bf2f(cv[5]) + d1.y);
          o[6] = f2bf(bf2f(cv[6]) + d1.z); o[7] = f2bf(bf2f(cv[7]) + d1.w);
          *(u16x8*)&kbf[hidx] = o;
        }
      }
    }
  }
}

// ---------------------------------------------------------------------------
// Out GEMM: 64x128 tile, BK=32, single-barrier 3-deep loop, unpinned sched.
// ---------------------------------------------------------------------------
__global__ __launch_bounds__(256) void gemm_out(
    const u16* __restrict__ Abf, const u16* __restrict__ Wt,
    const float* __restrict__ bias, float* __restrict__ outf) {
  __shared__ __align__(16) u16 As[3][64 * 32];
  __shared__ __align__(16) u16 Bs[3][128 * 32];

  const int m0 = blockIdx.y * 64, n0 = blockIdx.x * 128;
  const int tid = threadIdx.x;
  const int w = tid >> 6, l = tid & 63, li = l & 15, lg = l >> 4;
  const int wr = w >> 1, wc = w & 1;

  f32x4 acc[2][4];
  #pragma unroll
  for (int i = 0; i < 2; ++i)
    #pragma unroll
    for (int j = 0; j < 4; ++j) acc[i][j] = f32x4{0.f, 0.f, 0.f, 0.f};

  const u16* Ab = Abf + (size_t)m0 * DMODEL;
  const u16* Bb = Wt + (size_t)n0 * DMODEL;

  stage_tile<64>(As[0], Ab, tid);
  stage_tile<128>(Bs[0], Bb, tid);
  stage_tile<64>(As[1], Ab + 32, tid);
  stage_tile<128>(Bs[1], Bb + 32, tid);

  #pragma unroll
  for (int kt = 0; kt < 16; ++kt) {
    if (kt <= 14) asm volatile("s_waitcnt vmcnt(3)" ::: "memory");
    else          asm volatile("s_waitcnt vmcnt(0)" ::: "memory");
    __builtin_amdgcn_s_barrier();
    __builtin_amdgcn_sched_barrier(0);
    const u16* Asb = As[kt % 3];
    const u16* Bsb = Bs[kt % 3];
    u16x8 af[2], bfr[4];
    #pragma unroll
    for (int mt = 0; mt < 2; ++mt)
      af[mt] = *(const u16x8*)&Asb[swz_off(wr * 32 + mt * 16 + li, lg)];
    #pragma unroll
    for (int nt = 0; nt < 4; ++nt)
      bfr[nt] = *(const u16x8*)&Bsb[swz_off(wc * 64 + nt * 16 + li, lg)];
    if (kt + 2 < 16) {
      stage_tile<64>(As[(kt + 2) % 3], Ab + (kt + 2) * 32, tid);
      stage_tile<128>(Bs[(kt + 2) % 3], Bb + (kt + 2) * 32, tid);
    }
    #pragma unroll
    for (int mt = 0; mt < 2; ++mt)
      #pragma unroll
      for (int nt = 0; nt < 4; ++nt)
        acc[mt][nt] = mfma_bf16(af[mt], bfr[nt], acc[mt][nt]);
  }

  #pragma unroll
  for (int nt = 0; nt < 4; ++nt) {
    const int colg = n0 + wc * 64 + nt * 16 + li;
    const float bv = bias[colg];
    #pragma unroll
    for (int mt = 0; mt < 2; ++mt) {
      #pragma unroll
      for (int r = 0; r < 4; ++r) {
        const int rowg = m0 + wr * 32 + mt * 16 + lg * 4 + r;
        outf[(size_t)rowg * DMODEL + colg] = acc[mt][nt][r] + bv;
      }
    }
  }
}

// ---------------------------------------------------------------------------
// Flash attention (round-16/17 verified: staged body + T14 async-STAGE).
// Slots: h0 x8 (0-7), h1 x4 (8-11), h2 x2 (12-13), h3..h7 direct (14-18).
// ---------------------------------------------------------------------------
__global__ __launch_bounds__(256) void attn_kernel(
    const u16* __restrict__ qbf, const u16* __restrict__ kbf,
    const u16* __restrict__ vbfT, const float* __restrict__ bias_tab,
    const float* __restrict__ if_gain, const u16* __restrict__ gate,
    u16* __restrict__ attn_out, u16* __restrict__ partO,
    float* __restrict__ partM, float* __restrict__ partL) {
  __shared__ __align__(16) u16 Ks[64][LP];   // [kv][hd]
  __shared__ __align__(16) u16 Vt[64][LP];   // [hd][kv]
  __shared__ __align__(16) u16 Pl[4][16][LP];

  static const int DMINW[8] = {408, 139, 26, 18, 11, 5, 1, 0};
  static const int DMAXW[8] = {2049, 702, 185, 29, 22, 15, 10, 7};
  static const int DMINS[8] = {412, 143, 30, 22, 15, 9, 5, 2};
  static const int SH[19] = {0,0,0,0,0,0,0,0, 1,1,1,1, 2,2, 3,4,5,6,7};
  static const int SC[19] = {0,1,2,3,4,5,6,7, 0,1,2,3, 0,1, 0,0,0,0,0};
  static const int SN[19] = {8,8,8,8,8,8,8,8, 4,4,4,4, 2,2, 1,1,1,1,1};

  const int slot = blockIdx.x >> 7;
  const int rem = blockIdx.x & 127;
  const int qt = 31 - (rem >> 2);
  const int b = rem & 3;
  const int h = SH[slot], ch = SC[slot], nc = SN[slot];
  const int bh = b * HNUM + h;
  const int q0 = qt * 64;
  const int tid = threadIdx.x;
  const int w = tid >> 6, l = tid & 63, li = l & 15, lg = l >> 4;

  const u16* qrow = qbf + ((size_t)bh * NSEQ + q0 + w * 16 + li) * HDIM;
  u16x8 qf0 = *(const u16x8*)(qrow + lg * 8);
  u16x8 qf1 = *(const u16x8*)(qrow + 32 + lg * 8);

  const bool pure = q0 >= DMINS[h];
  int kv_lo = 0, kv_hi = q0 + 64;
  if (pure) {
    int lo = q0 - DMAXW[h];
    kv_lo = (lo > 0 ? lo : 0) & ~63;
    kv_hi = q0 + 64 - DMINW[h];
  }
  const int t0 = kv_lo >> 6, t1 = (kv_hi - 1) >> 6;
  const int len = t1 - t0 + 1;
  const int ta = t0 + (len * ch) / nc;
  const int tb = t0 + (len * (ch + 1)) / nc - 1;

  const int srow = tid >> 2;
  const int scb = (tid & 3) << 4;
  const float* btab = bias_tab + h * NSEQ;

  // T14 prologue: load tile ta into registers
  u16x8 kr0, kr1, vr0, vr1;
  {
    const int kv0 = ta << 6;
    const size_t kbase = ((size_t)bh * NSEQ + kv0 + srow) * HDIM + scb;
    kr0 = *(const u16x8*)(kbf + kbase);
    kr1 = *(const u16x8*)(kbf + kbase + 8);
    const size_t vbase = ((size_t)bh * HDIM + srow) * NSEQ + kv0 + scb;
    vr0 = *(const u16x8*)(vbfT + vbase);
    vr1 = *(const u16x8*)(vbfT + vbase + 8);
  }

  float mrun = -INFINITY, lrun = 0.f;
  f32x4 O[4] = {{0.f,0.f,0.f,0.f},{0.f,0.f,0.f,0.f},
                {0.f,0.f,0.f,0.f},{0.f,0.f,0.f,0.f}};

  for (int tt = ta; tt <= tb; ++tt) {
    const int kv0 = tt << 6;
    // ---- write staged regs -> LDS ----
    *(u16x8*)&Ks[srow][scb] = kr0;
    *(u16x8*)&Ks[srow][scb + 8] = kr1;
    *(u16x8*)&Vt[srow][scb] = vr0;
    *(u16x8*)&Vt[srow][scb + 8] = vr1;
    __syncthreads();

    // ---- T14: issue NEXT tile's global loads (consumed next iteration) ----
    if (tt < tb) {
      const int kv1 = (tt + 1) << 6;
      const size_t kbase = ((size_t)bh * NSEQ + kv1 + srow) * HDIM + scb;
      kr0 = *(const u16x8*)(kbf + kbase);
      kr1 = *(const u16x8*)(kbf + kbase + 8);
      const size_t vbase = ((size_t)bh * HDIM + srow) * NSEQ + kv1 + scb;
      vr0 = *(const u16x8*)(vbfT + vbase);
      vr1 = *(const u16x8*)(vbfT + vbase + 8);
    }

    // ---- S^T = K Q^T : 4 j-tiles x (K=64 -> 2 mfma) ----
    f32x4 s[4];
    #pragma unroll
    for (int t = 0; t < 4; ++t) {
      u16x8 a0 = *(const u16x8*)&Ks[t * 16 + li][lg * 8];
      u16x8 a1 = *(const u16x8*)&Ks[t * 16 + li][32 + lg * 8];
      f32x4 acc = {0.f, 0.f, 0.f, 0.f};
      acc = mfma_bf16(a0, qf0, acc);
      acc = mfma_bf16(a1, qf1, acc);
      s[t] = acc;
    }

    const int D0 = (q0 + w * 16 + li) - kv0 - lg * 4;
    float rm = -1e30f;
    #pragma unroll
    for (int t = 0; t < 4; ++t) {
      #pragma unroll
      for (int r = 0; r < 4; ++r) {
        int d = D0 - 16 * t - r;
        float sv = s[t][r];
        sv = (d >= 0) ? (sv + btab[d]) : -1e30f;
        s[t][r] = sv;
        rm = fmaxf(rm, sv);
      }
    }
    rm = fmaxf(rm, __shfl_xor(rm, 16, 64));
    rm = fmaxf(rm, __shfl_xor(rm, 32, 64));
    const float mn = fmaxf(mrun, rm);
    const float f = __expf(mrun - mn);
    mrun = mn;
    float ps = 0.f;
    #pragma unroll
    for (int t = 0; t < 4; ++t) {
      #pragma unroll
      for (int r = 0; r < 4; ++r) {
        float p = __expf(s[t][r] - mn);
        s[t][r] = p;
        ps += p;
      }
    }
    ps += __shfl_xor(ps, 16, 64);
    ps += __shfl_xor(ps, 32, 64);
    lrun = lrun * f + ps;

    #pragma unroll
    for (int t = 0; t < 4; ++t) {
      u16x4 pk;
      pk[0] = f2bf(s[t][0]); pk[1] = f2bf(s[t][1]);
      pk[2] = f2bf(s[t][2]); pk[3] = f2bf(s[t][3]);
      *(u16x4*)&Pl[w][li][t * 16 + lg * 4] = pk;
    }

    float fr[4];
    #pragma unroll
    for (int r = 0; r < 4; ++r) fr[r] = __shfl(f, lg * 4 + r, 64);
    #pragma unroll
    for (int dt = 0; dt < 4; ++dt) {
      O[dt][0] *= fr[0]; O[dt][1] *= fr[1];
      O[dt][2] *= fr[2]; O[dt][3] *= fr[3];
    }
    __syncthreads();

    #pragma unroll
    for (int ks = 0; ks < 2; ++ks) {
      u16x8 pA = *(const u16x8*)&Pl[w][li][ks * 32 + lg * 8];
      #pragma unroll
      for (int dt = 0; dt < 4; ++dt) {
        u16x8 vB = *(const u16x8*)&Vt[dt * 16 + li][ks * 32 + lg * 8];
        O[dt] = mfma_bf16(pA, vB, O[dt]);
      }
    }
    __syncthreads();
  }

  if (nc == 1) {
    const float gain = if_gain[h];
    float linv[4];
    #pragma unroll
    for (int r = 0; r < 4; ++r)
      linv[r] = gain / __shfl(lrun, lg * 4 + r, 64);
    #pragma unroll
    for (int r = 0; r < 4; ++r) {
      const int i = q0 + w * 16 + lg * 4 + r;
      const size_t base = ((size_t)b * NSEQ + i) * DMODEL + h * HDIM + li;
      #pragma unroll
      for (int dt = 0; dt < 4; ++dt) {
        const float g = bf2f(gate[base + dt * 16]);
        attn_out[base + dt * 16] = f2bf(O[dt][r] * linv[r] * g);
      }
    }
  } else {
    const int sbase = (b * 32 + qt) * NSLOT + slot;   // slot in 0..13 here
    #pragma unroll
    for (int r = 0; r < 4; ++r) {
      const int rl = w * 16 + lg * 4 + r;
      #pragma unroll
      for (int dt = 0; dt < 4; ++dt)
        partO[(size_t)sbase * 4096 + rl * 64 + dt * 16 + li] = f2bf(O[dt][r]);
    }
    if (lg == 0) {
      partM[sbase * 64 + w * 16 + li] = mrun;
      partL[sbase * 64 + w * 16 + li] = lrun;
    }
  }
}

// ---------------------------------------------------------------------------
// Combine split-KV partials: h0 (8 chunks), h1 (4), h2 (2).
// ---------------------------------------------------------------------------
__global__ __launch_bounds__(256) void combine_kernel(
    const u16* __restrict__ partO, const float* __restrict__ partM,
    const float* __restrict__ partL, const float* __restrict__ if_gain,
    const u16* __restrict__ gate, u16* __restrict__ attn_out) {
  const int b = blockIdx.x & 3, qt = blockIdx.x >> 2;
  const int tid = threadIdx.x;
  const int row = tid >> 2, d0 = (tid & 3) << 4;
  static const int HNC[3] = {8, 4, 2};
  static const int HS0[3] = {0, 8, 12};

  #pragma unroll
  for (int hc = 0; hc < 3; ++hc) {
    const int nc = HNC[hc], s0 = HS0[hc];
    const int sbase = (b * 32 + qt) * NSLOT + s0;
    float m[8];
    float M = -INFINITY;
    #pragma unroll
    for (int c = 0; c < 8; ++c) {
      m[c] = (c < nc) ? partM[(sbase + c) * 64 + row] : -INFINITY;
      M = fmaxf(M, m[c]);
    }
    float wch[8];
    float den = 0.f;
    #pragma unroll
    for (int c = 0; c < 8; ++c) {
      wch[c] = (c < nc) ? __expf(m[c] - M) : 0.f;
      if (c < nc) den += wch[c] * partL[(sbase + c) * 64 + row];
    }
    float num[16];
    #pragma unroll
    for (int j = 0; j < 16; ++j) num[j] = 0.f;
    #pragma unroll
    for (int c = 0; c < 8; ++c) {
      if (c < nc) {
        const u16* op = partO + (size_t)(sbase + c) * 4096 + row * 64 + d0;
        u16x8 o0 = *(const u16x8*)op;
        u16x8 o1 = *(const u16x8*)(op + 8);
        #pragma unroll
        for (int j = 0; j < 8; ++j) {
          num[j]     += wch[c] * bf2f(o0[j]);
          num[8 + j] += wch[c] * bf2f(o1[j]);
        }
      }
    }
    const float inv = if_gain[hc] / den;
    const size_t obase =
        ((size_t)b * NSEQ + qt * 64 + row) * DMODEL + hc * HDIM + d0;
    u16x8 g0 = *(const u16x8*)(gate + obase);
    u16x8 g1 = *(const u16x8*)(gate + obase + 8);
    u16x8 r0, r1;
    #pragma unroll
    for (int j = 0; j < 8; ++j) {
      r0[j] = f2bf(num[j] * inv * bf2f(g0[j]));
      r1[j] = f2bf(num[8 + j] * inv * bf2f(g1[j]));
    }
    *(u16x8*)(attn_out + obase) = r0;
    *(u16x8*)(attn_out + obase + 8) = r1;
  }
}

// ---------------------------------------------------------------------------
extern "C" void kernel_launch(void* const* d_in, const int* in_sizes, int n_in,
                              void* d_out, int out_size, void* d_ws,
                              size_t ws_size, hipStream_t stream) {
  const float* x       = (const float*)d_in[0];
  const float* k_delta = (const float*)d_in[1];
  const float* v_delta = (const float*)d_in[2];
  const float* qkv_w   = (const float*)d_in[3];
  const float* qkv_b   = (const float*)d_in[4];
  const float* gate_w  = (const float*)d_in[5];
  const float* gate_b  = (const float*)d_in[6];
  const float* out_w   = (const float*)d_in[7];
  const float* out_b   = (const float*)d_in[8];
  const float* pos_bias = (const float*)d_in[9];
  const float* if_gain  = (const float*)d_in[10];
  float* out = (float*)d_out;
  char* ws = (char*)d_ws;

  // workspace layout (bytes)
  u16*   xbf      = (u16*)(ws + 0);              //  8,388,608 (dead after gemm)
  u16*   qbf      = (u16*)(ws + 8388608);        //  8,388,608
  u16*   kbf      = (u16*)(ws + 16777216);       //  8,388,608
  u16*   attn_buf = (u16*)(ws + 25165824);       //  8,388,608
  u16*   vbfT     = (u16*)(ws + 33554432);       //  8,388,608
  u16*   gate_buf = (u16*)(ws + 41943040);       //  8,388,608
  u16*   fused_wt = (u16*)(ws + 50331648);       //  2,097,152
  u16*   out_wt   = (u16*)(ws + 52428800);       //    524,288
  float* bias_tab = (float*)(ws + 52953088);     //     65,536
  u16*   partO = (u16*)(ws + 53018624);          // 14,680,064
  float* partM = (float*)(ws + 67698688);        //    458,752
  float* partL = (float*)(ws + 68157440);        //    458,752

  // merged prep (cvt + weight transposes + bias table)
  prep_kernel<<<dim3(3336), dim3(256), 0, stream>>>(
      x, qkv_w, gate_w, out_w, pos_bias, xbf, fused_wt, out_wt, bias_tab);

  // fused qkv+gate GEMM (V written transposed directly -> vbfT)
  gemm_fused<<<dim3(512), dim3(512), 0, stream>>>(
      xbf, fused_wt, qkv_b, gate_b, k_delta, v_delta,
      qbf, kbf, vbfT, gate_buf);

  // flash attention: split-KV balanced chunks (19 slots), T14 staged
  attn_kernel<<<dim3(2432), dim3(256), 0, stream>>>(
      qbf, kbf, vbfT, bias_tab, if_gain, gate_buf, attn_buf,
      partO, partM, partL);

  // merge h0/h1/h2 partials
  combine_kernel<<<dim3(128), dim3(256), 0, stream>>>(
      partO, partM, partL, if_gain, gate_buf, attn_buf);

  // final GEMM -> d_out (fp32)
  gemm_out<<<dim3(4, 128), dim3(256), 0, stream>>>(
      attn_buf, out_wt, out_b, out);

  (void)in_sizes; (void)n_in; (void)out_size; (void)ws_size;
}